// Round 6
// baseline (474.661 us; speedup 1.0000x reference)
//
#include <hip/hip_runtime.h>
#include <hip/hip_bf16.h>

// GCN 2-layer. msg[s] = dinv[s] * (x@W)[s] stored in bf16 (dinv folded at GEMM epilogue).
// out[v] = dinv[v] * (sum_{e:dst=v} msg[src] + msg[v]) + b ; layer1 relu.
// GEMMs: MFMA 16x16x32 bf16, 2-term split (~fp32 accuracy), x tile in LDS.
// Aggregation: persistent grid-stride, one node per wave, shuffle reduce at END only.
// --- Session ledger ---
// R7: never fuse the latency-bound gather into an LDS-heavy MFMA kernel (occupancy).
// R8: nt stores only on >=64B-contiguous sectors (8B scattered nt = 4x write amp).
// R9: flat agg is TRAFFIC-bound (deeper MLP: zero delta). FETCH 193MB ~= 8 XCDs x
//     25.6MB msg1 = per-XCD L2 compulsory floor at ~3.8TB/s service rate.
// R10: chunk-major + XCD pinning IS L2-resident (FETCH->46MB) but shuffle-reduce
//     x8 visits = DS-pipe bound (383us). R11: per-lane serial walk = transaction
//     bound (117us). Chunked agg structurally dominated; flat agg 66us = floor.
// R12: 2-kernel CSR build + merged prep + float4 staging -> 348us total. Aggs at
//     floor; ~225us lives OUTSIDE aggs (invisible below top-5 cutoff).
// R13: CSR build was ~1 block/CU latency-bound serial loops + a 25.6MB tmp round
//     trip. Replace with device-wide atomics (order-free since sum is commutative):
//     count (atomicAdd deg) -> per-bucket scan (bucket-strided csr, no global scan)
//     -> fill (csr[atomicAdd(cursor[dst])]=src). Full occupancy, no tmp.

#define BSH 8
#define BCAP 8192  // csr slots per bucket (mean 4096, sigma 64 -> 64-sigma slack)
#define PREPB 104  // blocks 0..103 of k_prep_count do weight pre-split (26624/256)
#define CNTB 1024

typedef __attribute__((ext_vector_type(8))) short short8;
typedef __attribute__((ext_vector_type(4))) float float4v;
typedef __attribute__((ext_vector_type(2))) float float2v;

__device__ __forceinline__ float bf_lo(unsigned u) { return __uint_as_float(u << 16); }
__device__ __forceinline__ float bf_hi(unsigned u) { return __uint_as_float(u & 0xffff0000u); }
__device__ __forceinline__ float bf2f(unsigned short h) {
    return __uint_as_float((unsigned)h << 16);
}
__device__ __forceinline__ unsigned short f2bf(float f) {
    unsigned u = __float_as_uint(f);
    u += 0x7fff + ((u >> 16) & 1);  // round-to-nearest-even
    return (unsigned short)(u >> 16);
}
__device__ __forceinline__ void acc8(float* acc, uint4 m) {
    acc[0] += bf_lo(m.x); acc[1] += bf_hi(m.x);
    acc[2] += bf_lo(m.y); acc[3] += bf_hi(m.y);
    acc[4] += bf_lo(m.z); acc[5] += bf_hi(m.z);
    acc[6] += bf_lo(m.w); acc[7] += bf_hi(m.w);
}

// ---------------- fused: W pre-split (blocks < PREPB) + degree count ----------------
__global__ void k_prep_count(const float* __restrict__ W1, const float* __restrict__ W2,
                             unsigned short* __restrict__ w1th, unsigned short* __restrict__ w1tl,
                             unsigned short* __restrict__ w2th, unsigned short* __restrict__ w2tl,
                             const int* __restrict__ dst, int* __restrict__ deg, int E) {
    if (blockIdx.x < PREPB) {
        int i = blockIdx.x * 256 + threadIdx.x;
        if (i < 128 * 128) {
            int col = i % 128, k = i / 128;
            float w = W1[k * 128 + col];
            unsigned short h = f2bf(w);
            w1th[(size_t)col * 128 + k] = h;
            w1tl[(size_t)col * 128 + k] = f2bf(w - bf2f(h));
        } else if (i < 128 * 128 + 80 * 128) {
            int j = i - 128 * 128;
            int col = j % 80, k = j / 80;
            float w = (col < 70) ? W2[k * 70 + col] : 0.f;
            unsigned short h = f2bf(w);
            w2th[(size_t)col * 128 + k] = h;
            w2tl[(size_t)col * 128 + k] = f2bf(w - bf2f(h));
        }
        return;
    }
    int tid = (blockIdx.x - PREPB) * 256 + threadIdx.x;
    int stride = CNTB * 256;
    int E4 = E >> 2;
    for (int i = tid; i < E4; i += stride) {
        int4 d4 = ((const int4*)dst)[i];
        atomicAdd(&deg[d4.x], 1);
        atomicAdd(&deg[d4.y], 1);
        atomicAdd(&deg[d4.z], 1);
        atomicAdd(&deg[d4.w], 1);
    }
    for (int e = E4 * 4 + tid; e < E; e += stride) atomicAdd(&deg[dst[e]], 1);
}

// ---------------- per-bucket scan: rs/cursor/dinv (bucket-strided csr) ----------------
__global__ void k_scan_rs(const int* __restrict__ deg, float* __restrict__ dinv,
                          int* __restrict__ rs, int* __restrict__ cursor, int N) {
    __shared__ int sc[256];
    int b = blockIdx.x;
    int t = threadIdx.x;
    int node = (b << BSH) + t;
    int c = (node < N) ? deg[node] : 0;
    sc[t] = c;
    __syncthreads();
    for (int off = 1; off < 256; off <<= 1) {
        int add = (t >= off) ? sc[t - off] : 0;
        __syncthreads();
        sc[t] += add;
        __syncthreads();
    }
    int excl = sc[t] - c;
    if (node < N) {
        int base = b * BCAP + min(excl, BCAP);
        rs[node] = base;
        cursor[node] = base;
        dinv[node] = rsqrtf((float)(c + 1));
    }
}

// ---------------- csr fill: order-free (aggregation sum is commutative) ----------------
__global__ void k_fill(const int* __restrict__ src, const int* __restrict__ dst,
                       int* __restrict__ cursor, int* __restrict__ csr, int E) {
    int tid = blockIdx.x * 256 + threadIdx.x;
    int stride = gridDim.x * 256;
    int E4 = E >> 2;
    for (int i = tid; i < E4; i += stride) {
        int4 d4 = ((const int4*)dst)[i];
        int4 s4 = ((const int4*)src)[i];
        int p0 = atomicAdd(&cursor[d4.x], 1);
        int p1 = atomicAdd(&cursor[d4.y], 1);
        int p2 = atomicAdd(&cursor[d4.z], 1);
        int p3 = atomicAdd(&cursor[d4.w], 1);
        if (p0 < ((d4.x >> BSH) + 1) * BCAP) csr[p0] = s4.x;
        if (p1 < ((d4.y >> BSH) + 1) * BCAP) csr[p1] = s4.y;
        if (p2 < ((d4.z >> BSH) + 1) * BCAP) csr[p2] = s4.z;
        if (p3 < ((d4.w >> BSH) + 1) * BCAP) csr[p3] = s4.w;
    }
    for (int e = E4 * 4 + tid; e < E; e += stride) {
        int d = dst[e];
        int p = atomicAdd(&cursor[d], 1);
        if (p < ((d >> BSH) + 1) * BCAP) csr[p] = src[e];
    }
}

// ---------------- MFMA GEMM (split-bf16, ~fp32 accuracy) ----------------
// Y[r,c] = bf16(dinv[r] * (X@W)[r,c]). Block: 4 waves, 64 rows, K=128.
// B frags loaded as 16B vectors from pre-split Wt. X staged via float4 nt loads.
template <int DOUT, int OSTRIDE, int NT>
__global__ __launch_bounds__(256, 3) void k_gemm_mfma(
        const float* __restrict__ X, const unsigned short* __restrict__ Wth,
        const unsigned short* __restrict__ Wtl,
        const float* __restrict__ dinv, unsigned short* __restrict__ Y, int n) {
    __shared__ short xs_h[64][136];
    __shared__ short xs_l[64][136];
    int t = threadIdx.x;
    int lane = t & 63, wave = t >> 6;
    int m16 = lane & 15, quad = lane >> 4;
    int r0 = blockIdx.x * 64;

    short8 bh[2][4], bl[2][4];
    int nt0 = wave, nt1 = wave + 4;
#pragma unroll
    for (int i = 0; i < 2; i++) {
        int nt = i ? nt1 : nt0;
        if (nt >= NT) continue;
        int col = nt * 16 + m16;  // < NT*16 <= padded Wt cols
#pragma unroll
        for (int kc = 0; kc < 4; kc++) {
            bh[i][kc] = *(const short8*)&Wth[(size_t)col * 128 + kc * 32 + quad * 8];
            bl[i][kc] = *(const short8*)&Wtl[(size_t)col * 128 + kc * 32 + quad * 8];
        }
    }

    for (int p = t; p < 64 * 32; p += 256) {
        int row = p >> 5;
        int k4 = p & 31;
        int gr = r0 + row;
        if (gr >= n) gr = n - 1;
        float4v xv = __builtin_nontemporal_load(
            (const float4v*)(X + (size_t)gr * 128 + 4 * k4));
        unsigned short h0 = f2bf(xv.x), h1 = f2bf(xv.y);
        unsigned short h2 = f2bf(xv.z), h3 = f2bf(xv.w);
        unsigned short l0 = f2bf(xv.x - bf2f(h0)), l1 = f2bf(xv.y - bf2f(h1));
        unsigned short l2 = f2bf(xv.z - bf2f(h2)), l3 = f2bf(xv.w - bf2f(h3));
        *(uint2*)&xs_h[row][4 * k4] =
            make_uint2((unsigned)h0 | ((unsigned)h1 << 16), (unsigned)h2 | ((unsigned)h3 << 16));
        *(uint2*)&xs_l[row][4 * k4] =
            make_uint2((unsigned)l0 | ((unsigned)l1 << 16), (unsigned)l2 | ((unsigned)l3 << 16));
    }
    __syncthreads();

    float4v acc[2][4];
#pragma unroll
    for (int i = 0; i < 2; i++)
#pragma unroll
        for (int ms = 0; ms < 4; ms++) acc[i][ms] = (float4v){0.f, 0.f, 0.f, 0.f};

#pragma unroll
    for (int kc = 0; kc < 4; kc++) {
#pragma unroll
        for (int ms = 0; ms < 4; ms++) {
            short8 ah = *(short8*)&xs_h[ms * 16 + m16][kc * 32 + quad * 8];
            short8 al = *(short8*)&xs_l[ms * 16 + m16][kc * 32 + quad * 8];
#pragma unroll
            for (int i = 0; i < 2; i++) {
                int nt = i ? nt1 : nt0;
                if (nt >= NT) continue;
                acc[i][ms] = __builtin_amdgcn_mfma_f32_16x16x32_bf16(ah, bh[i][kc], acc[i][ms], 0, 0, 0);
                acc[i][ms] = __builtin_amdgcn_mfma_f32_16x16x32_bf16(al, bh[i][kc], acc[i][ms], 0, 0, 0);
                acc[i][ms] = __builtin_amdgcn_mfma_f32_16x16x32_bf16(ah, bl[i][kc], acc[i][ms], 0, 0, 0);
            }
        }
    }

#pragma unroll
    for (int i = 0; i < 2; i++) {
        int nt = i ? nt1 : nt0;
        if (nt >= NT) continue;
        int col = nt * 16 + m16;
        if (col >= OSTRIDE) continue;
#pragma unroll
        for (int ms = 0; ms < 4; ms++) {
#pragma unroll
            for (int r = 0; r < 4; r++) {
                int row = r0 + ms * 16 + quad * 4 + r;
                if (row < n) {
                    float val = (col < DOUT) ? acc[i][ms][r] * dinv[row] : 0.f;
                    Y[(size_t)row * OSTRIDE + col] = f2bf(val);
                }
            }
        }
    }
}

// ---------------- agg1: persistent, one node per wave, 4 slots x 4-in-flight ----------------
__global__ __launch_bounds__(256, 8) void k_agg_w128(
        const uint4* __restrict__ msg, const float* __restrict__ dinv,
        const int* __restrict__ rs, const int* __restrict__ deg,
        const int* __restrict__ csr, const float* __restrict__ bias,
        float* __restrict__ out, int n) {
    int lane = threadIdx.x & 63;
    int q = lane & 15;
    int slot = lane >> 4;
    int wid = blockIdx.x * 4 + (threadIdx.x >> 6);
    int nw = gridDim.x * 4;
    for (int v = wid; v < n; v += nw) {
        int start = rs[v];
        int cnt = deg[v];
        float dv = dinv[v];
        uint4 mself = msg[(size_t)v * 16 + q];
        float acc[8] = {0.f, 0.f, 0.f, 0.f, 0.f, 0.f, 0.f, 0.f};
        int i = slot;
        for (; i + 12 < cnt; i += 16) {  // 4 gathers in flight per slot
            int s0 = csr[start + i];
            int s1 = csr[start + i + 4];
            int s2 = csr[start + i + 8];
            int s3 = csr[start + i + 12];
            uint4 m0 = msg[(size_t)s0 * 16 + q];
            uint4 m1 = msg[(size_t)s1 * 16 + q];
            uint4 m2 = msg[(size_t)s2 * 16 + q];
            uint4 m3 = msg[(size_t)s3 * 16 + q];
            acc8(acc, m0);
            acc8(acc, m1);
            acc8(acc, m2);
            acc8(acc, m3);
        }
        for (; i + 4 < cnt; i += 8) {  // 2 in flight
            int s0 = csr[start + i];
            int s1 = csr[start + i + 4];
            uint4 m0 = msg[(size_t)s0 * 16 + q];
            uint4 m1 = msg[(size_t)s1 * 16 + q];
            acc8(acc, m0);
            acc8(acc, m1);
        }
        if (i < cnt) {
            int s = csr[start + i];
            uint4 m = msg[(size_t)s * 16 + q];
            acc8(acc, m);
        }
#pragma unroll
        for (int j = 0; j < 8; j++) acc[j] += __shfl_xor(acc[j], 32);
#pragma unroll
        for (int j = 0; j < 8; j++) acc[j] += __shfl_xor(acc[j], 16);
        if (slot == 0) {
            float o[8];
            o[0] = acc[0] + bf_lo(mself.x); o[1] = acc[1] + bf_hi(mself.x);
            o[2] = acc[2] + bf_lo(mself.y); o[3] = acc[3] + bf_hi(mself.y);
            o[4] = acc[4] + bf_lo(mself.z); o[5] = acc[5] + bf_hi(mself.z);
            o[6] = acc[6] + bf_lo(mself.w); o[7] = acc[7] + bf_hi(mself.w);
            float r[8];
#pragma unroll
            for (int j = 0; j < 8; j++) r[j] = fmaxf(dv * o[j] + bias[8 * q + j], 0.f);
            float4v* op = (float4v*)(out + (size_t)v * 128 + 8 * q);
            __builtin_nontemporal_store((float4v){r[0], r[1], r[2], r[3]}, op);
            __builtin_nontemporal_store((float4v){r[4], r[5], r[6], r[7]}, op + 1);
        }
    }
}

// ---------------- agg2: persistent, one node per wave, 7 slots x 9 lanes, 3-in-flight ----------------
__global__ __launch_bounds__(256, 8) void k_agg_w72(
        const uint4* __restrict__ msg, const float* __restrict__ dinv,
        const int* __restrict__ rs, const int* __restrict__ deg,
        const int* __restrict__ csr, const float* __restrict__ bias,
        float* __restrict__ out, int n) {
    int lane = threadIdx.x & 63;
    int slot = lane / 9;
    int q = lane - slot * 9;
    bool active = lane < 63;
    int wid = blockIdx.x * 4 + (threadIdx.x >> 6);
    int nw = gridDim.x * 4;
    for (int v = wid; v < n; v += nw) {
        int start = rs[v];
        int cnt = deg[v];
        float dv = dinv[v];
        float acc[8] = {0.f, 0.f, 0.f, 0.f, 0.f, 0.f, 0.f, 0.f};
        uint4 mself = make_uint4(0, 0, 0, 0);
        if (active) {
            mself = msg[(size_t)v * 9 + q];
            int i = slot;
            for (; i + 14 < cnt; i += 21) {  // 3 gathers in flight per slot
                int s0 = csr[start + i];
                int s1 = csr[start + i + 7];
                int s2 = csr[start + i + 14];
                uint4 m0 = msg[(size_t)s0 * 9 + q];
                uint4 m1 = msg[(size_t)s1 * 9 + q];
                uint4 m2 = msg[(size_t)s2 * 9 + q];
                acc8(acc, m0);
                acc8(acc, m1);
                acc8(acc, m2);
            }
            for (; i + 7 < cnt; i += 14) {
                int s0 = csr[start + i];
                int s1 = csr[start + i + 7];
                uint4 m0 = msg[(size_t)s0 * 9 + q];
                uint4 m1 = msg[(size_t)s1 * 9 + q];
                acc8(acc, m0);
                acc8(acc, m1);
            }
            if (i < cnt) {
                int s = csr[start + i];
                uint4 m = msg[(size_t)s * 9 + q];
                acc8(acc, m);
            }
        }
#pragma unroll
        for (int j = 0; j < 8; j++) {
            float t27 = __shfl(acc[j], lane + 27);
            if (lane < 27) acc[j] += t27;
        }
#pragma unroll
        for (int j = 0; j < 8; j++) {
            float t54 = __shfl(acc[j], lane + 54);
            float t9  = __shfl(acc[j], lane + 9);
            float t18 = __shfl(acc[j], lane + 18);
            if (lane < 9) acc[j] += t54 + t9 + t18;
        }
        if (lane < 9) {
            float o[8];
            o[0] = acc[0] + bf_lo(mself.x); o[1] = acc[1] + bf_hi(mself.x);
            o[2] = acc[2] + bf_lo(mself.y); o[3] = acc[3] + bf_hi(mself.y);
            o[4] = acc[4] + bf_lo(mself.z); o[5] = acc[5] + bf_hi(mself.z);
            o[6] = acc[6] + bf_lo(mself.w); o[7] = acc[7] + bf_hi(mself.w);
            float* orow = out + (size_t)v * 70 + 8 * q;
#pragma unroll
            for (int jj = 0; jj < 4; jj++) {
                int f = 8 * q + 2 * jj;
                if (f < 70) {
                    float2 st = make_float2(dv * o[2 * jj] + bias[f],
                                            dv * o[2 * jj + 1] + bias[f + 1]);
                    *(float2*)(orow + 2 * jj) = st;  // cached: L2 coalesces partial lines
                }
            }
        }
    }
}

static inline size_t alignup(size_t x) { return (x + 255) & ~(size_t)255; }

extern "C" void kernel_launch(void* const* d_in, const int* in_sizes, int n_in,
                              void* d_out, int out_size, void* d_ws, size_t ws_size,
                              hipStream_t stream) {
    const float* x = (const float*)d_in[0];
    const int* edge = (const int*)d_in[1];
    const float* W1 = (const float*)d_in[2];
    const float* b1 = (const float*)d_in[3];
    const float* W2 = (const float*)d_in[4];
    const float* b2 = (const float*)d_in[5];

    const int N = in_sizes[0] / 128;
    const int E = in_sizes[1] / 2;
    const int* src = edge;
    const int* dst = edge + E;
    const int nb = (N + 255) >> BSH;

    char* w = (char*)d_ws;
    int* deg = (int*)w;              w += alignup((size_t)N * 4);
    float* dinv = (float*)w;         w += alignup((size_t)N * 4);
    int* rs = (int*)w;               w += alignup((size_t)N * 4);
    int* cursor = (int*)w;           w += alignup((size_t)N * 4);
    int* csr = (int*)w;              w += alignup((size_t)nb * BCAP * 4);
    unsigned short* msg1 = (unsigned short*)w; w += alignup((size_t)N * 128 * 2);
    unsigned short* msg2 = (unsigned short*)w; w += alignup((size_t)N * 72 * 2);
    unsigned short* w1th = (unsigned short*)w; w += alignup(128 * 128 * 2);
    unsigned short* w1tl = (unsigned short*)w; w += alignup(128 * 128 * 2);
    unsigned short* w2th = (unsigned short*)w; w += alignup(80 * 128 * 2);
    unsigned short* w2tl = (unsigned short*)w; w += alignup(80 * 128 * 2);
    float* h = (float*)w;            w += alignup((size_t)N * 128 * 4);

    // ---- CSR build: count -> per-bucket scan -> order-free fill ----
    hipMemsetAsync(deg, 0, (size_t)N * 4, stream);
    k_prep_count<<<PREPB + CNTB, 256, 0, stream>>>(W1, W2, w1th, w1tl, w2th, w2tl,
                                                   dst, deg, E);
    k_scan_rs<<<nb, 256, 0, stream>>>(deg, dinv, rs, cursor, N);
    k_fill<<<1024, 256, 0, stream>>>(src, dst, cursor, csr, E);

    int gblocks = (N + 63) / 64;

    // Layer 1: msg1 = bf16(dinv * (x @ W1)) [N,128] ; agg -> h [N,128] fp32 (bias+relu)
    k_gemm_mfma<128, 128, 8><<<gblocks, 256, 0, stream>>>(x, w1th, w1tl, dinv, msg1, N);
    k_agg_w128<<<2048, 256, 0, stream>>>((const uint4*)msg1, dinv, rs, deg, csr, b1, h, N);

    // Layer 2: msg2 = bf16(dinv * (h @ W2)) [N,72 pad] ; agg -> d_out [N,70] (bias)
    k_gemm_mfma<70, 72, 5><<<gblocks, 256, 0, stream>>>(h, w2th, w2tl, dinv, msg2, N);
    k_agg_w72<<<2048, 256, 0, stream>>>((const uint4*)msg2, dinv, rs, deg, csr, b2,
                                        (float*)d_out, N);
}

// Round 7
// 351.020 us; speedup vs baseline: 1.3522x; 1.3522x over previous
//
#include <hip/hip_runtime.h>
#include <hip/hip_bf16.h>

// GCN 2-layer. msg[s] = dinv[s] * (x@W)[s] stored in bf16 (dinv folded at GEMM epilogue).
// out[v] = dinv[v] * (sum_{e:dst=v} msg[src] + msg[v]) + b ; layer1 relu.
// GEMMs: MFMA 16x16x32 bf16, 2-term split (~fp32 accuracy), x tile in LDS.
// --- Session ledger ---
// R7: never fuse the latency-bound gather into an LDS-heavy MFMA kernel (occupancy).
// R8: nt stores only on >=64B-contiguous sectors (8B scattered nt = 4x write amp).
// R9: flat agg is TRAFFIC-bound (deeper MLP: zero delta).
// R9b: agg FETCH = sum over XCDs of DISTINCT msg rows touched (N/8 nodes/XCD ->
//     86k of 100k rows x 256B x 8 = 177MB + csr = 193 measured ✓).
// R10: blockIdx%8 -> XCD round-robin pinning CONFIRMED (FETCH 193->46) but
//     wave-per-node shuffle reduce x8 visits = DS-pipe bound (383us).
// R11: 32 nodes/wave per-lane serial walk = csr transaction + divergence bound (117us).
// R12: 2-kernel bucketed CSR build (clustered writes) + merged prep + float4 staging
//     -> 348us total (best).
// R13: device-wide-atomic CSR fill: random 4B csr stores = 16x write amp (107MB),
//     120us. REVERTED to R12 build.
// R14: half-split aggregation. msg layout [2][N][D/2]; half = blockIdx&1 -> even
//     XCDs own half0, odd own half1 (disjoint, per R10 pinning). Per-XCD distinct
//     bytes halve (12.6MB vs 22MB). Wave = 8 nodes x 8 featlanes (L2: 12x5), each
//     lane owns 8 feats and serially walks its node's edges (unroll 4) - ZERO
//     cross-lane ops, csr broadcast within node group.

#define BSH 8
#define BCHUNK 8192
#define BCAP 8192  // tmp/csr slots per bucket (mean 4096, 64-sigma slack)

typedef __attribute__((ext_vector_type(8))) short short8;
typedef __attribute__((ext_vector_type(4))) float float4v;
typedef __attribute__((ext_vector_type(2))) float float2v;

__device__ __forceinline__ float bf_lo(unsigned u) { return __uint_as_float(u << 16); }
__device__ __forceinline__ float bf_hi(unsigned u) { return __uint_as_float(u & 0xffff0000u); }
__device__ __forceinline__ float bf2f(unsigned short h) {
    return __uint_as_float((unsigned)h << 16);
}
__device__ __forceinline__ unsigned short f2bf(float f) {
    unsigned u = __float_as_uint(f);
    u += 0x7fff + ((u >> 16) & 1);  // round-to-nearest-even
    return (unsigned short)(u >> 16);
}
__device__ __forceinline__ void acc8(float* acc, uint4 m) {
    acc[0] += bf_lo(m.x); acc[1] += bf_hi(m.x);
    acc[2] += bf_lo(m.y); acc[3] += bf_hi(m.y);
    acc[4] += bf_lo(m.z); acc[5] += bf_hi(m.z);
    acc[6] += bf_lo(m.w); acc[7] += bf_hi(m.w);
}

// ---------------- CSR build (R12-proven: 2 kernels, clustered writes) ----------------
__global__ void k_bucket_scatter(const int* __restrict__ src, const int* __restrict__ dst,
                                 int* __restrict__ bwcur,
                                 unsigned long long* __restrict__ tmp, int E, int nb) {
    __shared__ int lh[512];
    __shared__ int lb[512];
    int t = threadIdx.x;
    for (int j = t; j < nb; j += 256) lh[j] = 0;
    __syncthreads();
    int e0 = blockIdx.x * BCHUNK;
    int e1 = min(E, e0 + BCHUNK);
    for (int e = e0 + t; e < e1; e += 256) atomicAdd(&lh[dst[e] >> BSH], 1);
    __syncthreads();
    for (int j = t; j < nb; j += 256) {
        int c = lh[j];
        lb[j] = c ? atomicAdd(&bwcur[j], c) : 0;
        lh[j] = 0;
    }
    __syncthreads();
    for (int e = e0 + t; e < e1; e += 256) {
        int d = dst[e];
        int b = d >> BSH;
        int o = atomicAdd(&lh[b], 1);
        int pos = lb[b] + o;
        if (pos < BCAP)  // memory-safe clamp
            tmp[(size_t)b * BCAP + pos] =
                ((unsigned long long)(unsigned)d << 32) | (unsigned)src[e];
    }
}

__global__ void k_bucket_finalize(const unsigned long long* __restrict__ tmp,
                                  const int* __restrict__ bwcur,
                                  int* __restrict__ deg, float* __restrict__ dinv,
                                  int* __restrict__ rs, int* __restrict__ csr, int N) {
    __shared__ int cnt[256];
    __shared__ int sc[256];
    int b = blockIdx.x;
    int t = threadIdx.x;
    int e0 = b * BCAP;
    int e1 = e0 + min(bwcur[b], BCAP);
    cnt[t] = 0;
    __syncthreads();
    for (int e = e0 + t; e < e1; e += 256) {
        int d = (int)(tmp[e] >> 32);
        atomicAdd(&cnt[d & 255], 1);
    }
    __syncthreads();
    int c = cnt[t];
    sc[t] = c;
    __syncthreads();
    for (int off = 1; off < 256; off <<= 1) {
        int add = (t >= off) ? sc[t - off] : 0;
        __syncthreads();
        sc[t] += add;
        __syncthreads();
    }
    int excl = sc[t] - c;
    __syncthreads();
    sc[t] = excl;
    int node = (b << BSH) + t;
    if (node < N) {
        deg[node] = c;
        dinv[node] = rsqrtf((float)(c + 1));
        rs[node] = e0 + excl;
    }
    cnt[t] = 0;
    __syncthreads();
    for (int e = e0 + t; e < e1; e += 256) {
        unsigned long long p = tmp[e];
        int j = ((int)(p >> 32)) & 255;
        int o = atomicAdd(&cnt[j], 1);
        csr[e0 + sc[j] + o] = (int)(p & 0xffffffffu);
    }
}

// ---------------- W pre-split (both layers, one launch) ----------------
__global__ void k_prep_w(const float* __restrict__ W1, const float* __restrict__ W2,
                         unsigned short* __restrict__ w1th, unsigned short* __restrict__ w1tl,
                         unsigned short* __restrict__ w2th, unsigned short* __restrict__ w2tl) {
    int i = blockIdx.x * blockDim.x + threadIdx.x;
    if (i < 128 * 128) {
        int col = i % 128, k = i / 128;
        float w = W1[k * 128 + col];
        unsigned short h = f2bf(w);
        w1th[(size_t)col * 128 + k] = h;
        w1tl[(size_t)col * 128 + k] = f2bf(w - bf2f(h));
    } else if (i < 128 * 128 + 80 * 128) {
        int j = i - 128 * 128;
        int col = j % 80, k = j / 80;
        float w = (col < 70) ? W2[k * 70 + col] : 0.f;
        unsigned short h = f2bf(w);
        w2th[(size_t)col * 128 + k] = h;
        w2tl[(size_t)col * 128 + k] = f2bf(w - bf2f(h));
    }
}

// ---------------- MFMA GEMM (split-bf16, ~fp32 accuracy) ----------------
// MODE 0: Y half-major [2][n][64]: Y[((col>>6)*n+row)*64 + (col&63)]
// MODE 1: Y half-major [2][n][40]: hf=(col>=40), Y[(hf*n+row)*40 + col-hf*40] (col<80)
template <int DOUT, int NT, int MODE>
__global__ __launch_bounds__(256, 3) void k_gemm_mfma(
        const float* __restrict__ X, const unsigned short* __restrict__ Wth,
        const unsigned short* __restrict__ Wtl,
        const float* __restrict__ dinv, unsigned short* __restrict__ Y, int n) {
    __shared__ short xs_h[64][136];
    __shared__ short xs_l[64][136];
    int t = threadIdx.x;
    int lane = t & 63, wave = t >> 6;
    int m16 = lane & 15, quad = lane >> 4;
    int r0 = blockIdx.x * 64;

    short8 bh[2][4], bl[2][4];
    int nt0 = wave, nt1 = wave + 4;
#pragma unroll
    for (int i = 0; i < 2; i++) {
        int nt = i ? nt1 : nt0;
        if (nt >= NT) continue;
        int col = nt * 16 + m16;  // < NT*16 <= padded Wt cols
#pragma unroll
        for (int kc = 0; kc < 4; kc++) {
            bh[i][kc] = *(const short8*)&Wth[(size_t)col * 128 + kc * 32 + quad * 8];
            bl[i][kc] = *(const short8*)&Wtl[(size_t)col * 128 + kc * 32 + quad * 8];
        }
    }

    for (int p = t; p < 64 * 32; p += 256) {
        int row = p >> 5;
        int k4 = p & 31;
        int gr = r0 + row;
        if (gr >= n) gr = n - 1;
        float4v xv = __builtin_nontemporal_load(
            (const float4v*)(X + (size_t)gr * 128 + 4 * k4));
        unsigned short h0 = f2bf(xv.x), h1 = f2bf(xv.y);
        unsigned short h2 = f2bf(xv.z), h3 = f2bf(xv.w);
        unsigned short l0 = f2bf(xv.x - bf2f(h0)), l1 = f2bf(xv.y - bf2f(h1));
        unsigned short l2 = f2bf(xv.z - bf2f(h2)), l3 = f2bf(xv.w - bf2f(h3));
        *(uint2*)&xs_h[row][4 * k4] =
            make_uint2((unsigned)h0 | ((unsigned)h1 << 16), (unsigned)h2 | ((unsigned)h3 << 16));
        *(uint2*)&xs_l[row][4 * k4] =
            make_uint2((unsigned)l0 | ((unsigned)l1 << 16), (unsigned)l2 | ((unsigned)l3 << 16));
    }
    __syncthreads();

    float4v acc[2][4];
#pragma unroll
    for (int i = 0; i < 2; i++)
#pragma unroll
        for (int ms = 0; ms < 4; ms++) acc[i][ms] = (float4v){0.f, 0.f, 0.f, 0.f};

#pragma unroll
    for (int kc = 0; kc < 4; kc++) {
#pragma unroll
        for (int ms = 0; ms < 4; ms++) {
            short8 ah = *(short8*)&xs_h[ms * 16 + m16][kc * 32 + quad * 8];
            short8 al = *(short8*)&xs_l[ms * 16 + m16][kc * 32 + quad * 8];
#pragma unroll
            for (int i = 0; i < 2; i++) {
                int nt = i ? nt1 : nt0;
                if (nt >= NT) continue;
                acc[i][ms] = __builtin_amdgcn_mfma_f32_16x16x32_bf16(ah, bh[i][kc], acc[i][ms], 0, 0, 0);
                acc[i][ms] = __builtin_amdgcn_mfma_f32_16x16x32_bf16(al, bh[i][kc], acc[i][ms], 0, 0, 0);
                acc[i][ms] = __builtin_amdgcn_mfma_f32_16x16x32_bf16(ah, bl[i][kc], acc[i][ms], 0, 0, 0);
            }
        }
    }

#pragma unroll
    for (int i = 0; i < 2; i++) {
        int nt = i ? nt1 : nt0;
        if (nt >= NT) continue;
        int col = nt * 16 + m16;
#pragma unroll
        for (int ms = 0; ms < 4; ms++) {
#pragma unroll
            for (int r = 0; r < 4; r++) {
                int row = r0 + ms * 16 + quad * 4 + r;
                if (row < n) {
                    float val = (col < DOUT) ? acc[i][ms][r] * dinv[row] : 0.f;
                    if (MODE == 0) {
                        int hf = col >> 6;
                        Y[(((size_t)hf * n + row) << 6) + (col & 63)] = f2bf(val);
                    } else {
                        int hf = (col >= 40) ? 1 : 0;
                        Y[((size_t)hf * n + row) * 40 + (col - hf * 40)] = f2bf(val);
                    }
                }
            }
        }
    }
}

// ---------------- half-split agg: NPW nodes/wave x FL featlanes, zero shuffles --------
// msg [2][n][DH uint4]; half = blockIdx&1 -> disjoint XCD sets (round-robin pinning).
// Each lane owns 8 feats of its node, serially walks edges unroll-4; csr reads
// broadcast within the node's FL lanes; direct per-lane epilogue store.
template <int FL, int NPW, int DH, bool RELU, int OSTRIDE, int HOFF, int DOUT, bool NTST>
__global__ __launch_bounds__(256, 8) void k_agg_half(
        const uint4* __restrict__ msg, const float* __restrict__ dinv,
        const int* __restrict__ rs, const int* __restrict__ deg,
        const int* __restrict__ csr, const float* __restrict__ bias,
        float* __restrict__ out, int n) {
    int half = blockIdx.x & 1;
    int wid = (blockIdx.x >> 1) * 4 + (threadIdx.x >> 6);
    int nw = (gridDim.x >> 1) * 4;
    int lane = threadIdx.x & 63;
    int g = lane / FL;
    int f = lane - g * FL;
    bool act = g < NPW;
    const uint4* mh = msg + (size_t)half * n * DH;
    for (int base = wid * NPW; base < n; base += nw * NPW) {
        int v = base + g;
        bool valid = act && (v < n);
        int start = 0, cnt = 0;
        float dv = 0.f;
        if (valid) { start = rs[v]; cnt = deg[v]; dv = dinv[v]; }
        float acc[8] = {0.f, 0.f, 0.f, 0.f, 0.f, 0.f, 0.f, 0.f};
        int i = 0;
        for (; i + 3 < cnt; i += 4) {  // 4 gathers in flight per lane
            int s0 = csr[start + i];
            int s1 = csr[start + i + 1];
            int s2 = csr[start + i + 2];
            int s3 = csr[start + i + 3];
            uint4 m0 = mh[(size_t)s0 * DH + f];
            uint4 m1 = mh[(size_t)s1 * DH + f];
            uint4 m2 = mh[(size_t)s2 * DH + f];
            uint4 m3 = mh[(size_t)s3 * DH + f];
            acc8(acc, m0);
            acc8(acc, m1);
            acc8(acc, m2);
            acc8(acc, m3);
        }
        for (; i < cnt; i++) {
            uint4 m = mh[(size_t)csr[start + i] * DH + f];
            acc8(acc, m);
        }
        if (valid) {
            uint4 ms = mh[(size_t)v * DH + f];
            float o[8];
            o[0] = acc[0] + bf_lo(ms.x); o[1] = acc[1] + bf_hi(ms.x);
            o[2] = acc[2] + bf_lo(ms.y); o[3] = acc[3] + bf_hi(ms.y);
            o[4] = acc[4] + bf_lo(ms.z); o[5] = acc[5] + bf_hi(ms.z);
            o[6] = acc[6] + bf_lo(ms.w); o[7] = acc[7] + bf_hi(ms.w);
            int f0 = half * HOFF + f * 8;
            float r[8];
#pragma unroll
            for (int j = 0; j < 8; j++) {
                float b = (f0 + j < DOUT) ? bias[f0 + j] : 0.f;
                float val = dv * o[j] + b;
                r[j] = RELU ? fmaxf(val, 0.f) : val;
            }
            if (NTST) {
                // 32B per lane, contiguous 256B per node-half: full-sector nt safe
                float4v* op = (float4v*)(out + (size_t)v * OSTRIDE + f0);
                __builtin_nontemporal_store((float4v){r[0], r[1], r[2], r[3]}, op);
                __builtin_nontemporal_store((float4v){r[4], r[5], r[6], r[7]}, op + 1);
            } else {
#pragma unroll
                for (int jj = 0; jj < 4; jj++) {
                    int fe = f0 + 2 * jj;
                    if (fe + 1 < DOUT) {
                        *(float2*)(out + (size_t)v * OSTRIDE + fe) =
                            make_float2(r[2 * jj], r[2 * jj + 1]);  // cached
                    }
                }
            }
        }
    }
}

static inline size_t alignup(size_t x) { return (x + 255) & ~(size_t)255; }

extern "C" void kernel_launch(void* const* d_in, const int* in_sizes, int n_in,
                              void* d_out, int out_size, void* d_ws, size_t ws_size,
                              hipStream_t stream) {
    const float* x = (const float*)d_in[0];
    const int* edge = (const int*)d_in[1];
    const float* W1 = (const float*)d_in[2];
    const float* b1 = (const float*)d_in[3];
    const float* W2 = (const float*)d_in[4];
    const float* b2 = (const float*)d_in[5];

    const int N = in_sizes[0] / 128;
    const int E = in_sizes[1] / 2;
    const int* src = edge;
    const int* dst = edge + E;
    const int nb = (N + 255) >> BSH;

    char* w = (char*)d_ws;
    int* deg = (int*)w;              w += alignup((size_t)N * 4);
    float* dinv = (float*)w;         w += alignup((size_t)N * 4);
    int* rs = (int*)w;               w += alignup((size_t)N * 4);
    int* bwcur = (int*)w;            w += alignup(4096);
    int* csr = (int*)w;              w += alignup((size_t)nb * BCAP * 4);
    unsigned short* msg1 = (unsigned short*)w; w += alignup((size_t)N * 128 * 2);
    unsigned short* msg2 = (unsigned short*)w; w += alignup((size_t)N * 80 * 2);
    unsigned short* w1th = (unsigned short*)w; w += alignup(128 * 128 * 2);
    unsigned short* w1tl = (unsigned short*)w; w += alignup(128 * 128 * 2);
    unsigned short* w2th = (unsigned short*)w; w += alignup(80 * 128 * 2);
    unsigned short* w2tl = (unsigned short*)w; w += alignup(80 * 128 * 2);
    float* h = (float*)w;            w += alignup((size_t)N * 128 * 4);
    unsigned long long* tmp = (unsigned long long*)h;  // aliases h (disjoint in time)

    // ---- W pre-split (one launch, both layers) ----
    k_prep_w<<<(128 * 128 + 80 * 128 + 255) / 256, 256, 0, stream>>>(
        W1, W2, w1th, w1tl, w2th, w2tl);

    // ---- CSR build (R12-proven) ----
    hipMemsetAsync(bwcur, 0, (size_t)nb * 4, stream);
    k_bucket_scatter<<<(E + BCHUNK - 1) / BCHUNK, 256, 0, stream>>>(src, dst, bwcur, tmp, E, nb);
    k_bucket_finalize<<<nb, 256, 0, stream>>>(tmp, bwcur, deg, dinv, rs, csr, N);

    int gblocks = (N + 63) / 64;

    // Layer 1: msg1 [2][N][64] bf16 ; agg -> h [N,128] fp32 (bias+relu)
    k_gemm_mfma<128, 8, 0><<<gblocks, 256, 0, stream>>>(x, w1th, w1tl, dinv, msg1, N);
    k_agg_half<8, 8, 8, true, 128, 64, 128, true><<<2048, 256, 0, stream>>>(
        (const uint4*)msg1, dinv, rs, deg, csr, b1, h, N);

    // Layer 2: msg2 [2][N][40] bf16 (cols 70..79 zero) ; agg -> d_out [N,70] (bias)
    k_gemm_mfma<70, 5, 1><<<gblocks, 256, 0, stream>>>(h, w2th, w2tl, dinv, msg2, N);
    k_agg_half<5, 12, 5, false, 70, 40, 70, false><<<2048, 256, 0, stream>>>(
        (const uint4*)msg2, dinv, rs, deg, csr, b2, (float*)d_out, N);
}

// Round 8
// 342.215 us; speedup vs baseline: 1.3870x; 1.0257x over previous
//
#include <hip/hip_runtime.h>
#include <hip/hip_bf16.h>

// GCN 2-layer. msg[s] = dinv[s] * (x@W)[s] stored in bf16 (dinv folded at GEMM epilogue).
// out[v] = dinv[v] * (sum_{e:dst=v} msg[src] + msg[v]) + b ; layer1 relu.
// GEMMs: MFMA 16x16x32 bf16, 2-term split (~fp32 accuracy), x tile in LDS.
// Aggregation: persistent grid-stride, one node per wave, shuffle reduce at END only.
// --- Session ledger (final) ---
// R7: never fuse the latency-bound gather into an LDS-heavy MFMA kernel (occupancy).
// R8: nt stores only on >=64B-contiguous sectors (8B scattered nt = 4x write amp).
// R9: flat agg is TRAFFIC-bound (deeper MLP: zero delta) at ~3.8TB/s L2-miss service.
// R10: blockIdx%8->XCD round-robin pinning real (FETCH 193->46MB) but 8 chunk-visits
//     x wave-shuffle-reduce = DS-pipe bound (383us).
// R11: chunked per-lane serial walk = csr transaction + divergence bound (117us).
// R13: device-wide-atomic csr fill = 16x write amplification on random 4B stores (120us).
// R14: half-split (12.8MB/XCD) gave ZERO fetch reduction -> per-XCD hit rate only
//     improves when pinned working set fits 4MB L2; all <=4MB structures lose more on
//     execution than they save on traffic. Flat agg = measured ceiling of this path.
// R12 (THIS CONFIG, session best 348us): flat aggs + 2-kernel bucketed CSR build
//     (clustered writes) + merged prep_w + float4 nt gemm staging.

#define BSH 8
#define BCHUNK 8192
#define BCAP 8192  // tmp/csr slots per bucket (mean 4096, 64-sigma slack)

typedef __attribute__((ext_vector_type(8))) short short8;
typedef __attribute__((ext_vector_type(4))) float float4v;
typedef __attribute__((ext_vector_type(2))) float float2v;

__device__ __forceinline__ float bf_lo(unsigned u) { return __uint_as_float(u << 16); }
__device__ __forceinline__ float bf_hi(unsigned u) { return __uint_as_float(u & 0xffff0000u); }
__device__ __forceinline__ float bf2f(unsigned short h) {
    return __uint_as_float((unsigned)h << 16);
}
__device__ __forceinline__ unsigned short f2bf(float f) {
    unsigned u = __float_as_uint(f);
    u += 0x7fff + ((u >> 16) & 1);  // round-to-nearest-even
    return (unsigned short)(u >> 16);
}
__device__ __forceinline__ void acc8(float* acc, uint4 m) {
    acc[0] += bf_lo(m.x); acc[1] += bf_hi(m.x);
    acc[2] += bf_lo(m.y); acc[3] += bf_hi(m.y);
    acc[4] += bf_lo(m.z); acc[5] += bf_hi(m.z);
    acc[6] += bf_lo(m.w); acc[7] += bf_hi(m.w);
}

// ---------------- CSR build (2 kernels, clustered writes) ----------------
__global__ void k_bucket_scatter(const int* __restrict__ src, const int* __restrict__ dst,
                                 int* __restrict__ bwcur,
                                 unsigned long long* __restrict__ tmp, int E, int nb) {
    __shared__ int lh[512];
    __shared__ int lb[512];
    int t = threadIdx.x;
    for (int j = t; j < nb; j += 256) lh[j] = 0;
    __syncthreads();
    int e0 = blockIdx.x * BCHUNK;
    int e1 = min(E, e0 + BCHUNK);
    for (int e = e0 + t; e < e1; e += 256) atomicAdd(&lh[dst[e] >> BSH], 1);
    __syncthreads();
    for (int j = t; j < nb; j += 256) {
        int c = lh[j];
        lb[j] = c ? atomicAdd(&bwcur[j], c) : 0;
        lh[j] = 0;
    }
    __syncthreads();
    for (int e = e0 + t; e < e1; e += 256) {
        int d = dst[e];
        int b = d >> BSH;
        int o = atomicAdd(&lh[b], 1);
        int pos = lb[b] + o;
        if (pos < BCAP)  // memory-safe clamp
            tmp[(size_t)b * BCAP + pos] =
                ((unsigned long long)(unsigned)d << 32) | (unsigned)src[e];
    }
}

__global__ void k_bucket_finalize(const unsigned long long* __restrict__ tmp,
                                  const int* __restrict__ bwcur,
                                  int* __restrict__ deg, float* __restrict__ dinv,
                                  int* __restrict__ rs, int* __restrict__ csr, int N) {
    __shared__ int cnt[256];
    __shared__ int sc[256];
    int b = blockIdx.x;
    int t = threadIdx.x;
    int e0 = b * BCAP;
    int e1 = e0 + min(bwcur[b], BCAP);
    cnt[t] = 0;
    __syncthreads();
    for (int e = e0 + t; e < e1; e += 256) {
        int d = (int)(tmp[e] >> 32);
        atomicAdd(&cnt[d & 255], 1);
    }
    __syncthreads();
    int c = cnt[t];
    sc[t] = c;
    __syncthreads();
    for (int off = 1; off < 256; off <<= 1) {
        int add = (t >= off) ? sc[t - off] : 0;
        __syncthreads();
        sc[t] += add;
        __syncthreads();
    }
    int excl = sc[t] - c;
    __syncthreads();
    sc[t] = excl;
    int node = (b << BSH) + t;
    if (node < N) {
        deg[node] = c;
        dinv[node] = rsqrtf((float)(c + 1));
        rs[node] = e0 + excl;
    }
    cnt[t] = 0;
    __syncthreads();
    for (int e = e0 + t; e < e1; e += 256) {
        unsigned long long p = tmp[e];
        int j = ((int)(p >> 32)) & 255;
        int o = atomicAdd(&cnt[j], 1);
        csr[e0 + sc[j] + o] = (int)(p & 0xffffffffu);
    }
}

// ---------------- W pre-split (both layers, one launch) ----------------
__global__ void k_prep_w(const float* __restrict__ W1, const float* __restrict__ W2,
                         unsigned short* __restrict__ w1th, unsigned short* __restrict__ w1tl,
                         unsigned short* __restrict__ w2th, unsigned short* __restrict__ w2tl) {
    int i = blockIdx.x * blockDim.x + threadIdx.x;
    if (i < 128 * 128) {
        int col = i % 128, k = i / 128;
        float w = W1[k * 128 + col];
        unsigned short h = f2bf(w);
        w1th[(size_t)col * 128 + k] = h;
        w1tl[(size_t)col * 128 + k] = f2bf(w - bf2f(h));
    } else if (i < 128 * 128 + 80 * 128) {
        int j = i - 128 * 128;
        int col = j % 80, k = j / 80;
        float w = (col < 70) ? W2[k * 70 + col] : 0.f;
        unsigned short h = f2bf(w);
        w2th[(size_t)col * 128 + k] = h;
        w2tl[(size_t)col * 128 + k] = f2bf(w - bf2f(h));
    }
}

// ---------------- MFMA GEMM (split-bf16, ~fp32 accuracy) ----------------
// Y[r,c] = bf16(dinv[r] * (X@W)[r,c]). Block: 4 waves, 64 rows, K=128.
// B frags loaded as 16B vectors from pre-split Wt. X staged via float4 nt loads.
template <int DOUT, int OSTRIDE, int NT>
__global__ __launch_bounds__(256, 3) void k_gemm_mfma(
        const float* __restrict__ X, const unsigned short* __restrict__ Wth,
        const unsigned short* __restrict__ Wtl,
        const float* __restrict__ dinv, unsigned short* __restrict__ Y, int n) {
    __shared__ short xs_h[64][136];
    __shared__ short xs_l[64][136];
    int t = threadIdx.x;
    int lane = t & 63, wave = t >> 6;
    int m16 = lane & 15, quad = lane >> 4;
    int r0 = blockIdx.x * 64;

    short8 bh[2][4], bl[2][4];
    int nt0 = wave, nt1 = wave + 4;
#pragma unroll
    for (int i = 0; i < 2; i++) {
        int nt = i ? nt1 : nt0;
        if (nt >= NT) continue;
        int col = nt * 16 + m16;  // < NT*16 <= padded Wt cols
#pragma unroll
        for (int kc = 0; kc < 4; kc++) {
            bh[i][kc] = *(const short8*)&Wth[(size_t)col * 128 + kc * 32 + quad * 8];
            bl[i][kc] = *(const short8*)&Wtl[(size_t)col * 128 + kc * 32 + quad * 8];
        }
    }

    for (int p = t; p < 64 * 32; p += 256) {
        int row = p >> 5;
        int k4 = p & 31;
        int gr = r0 + row;
        if (gr >= n) gr = n - 1;
        float4v xv = __builtin_nontemporal_load(
            (const float4v*)(X + (size_t)gr * 128 + 4 * k4));
        unsigned short h0 = f2bf(xv.x), h1 = f2bf(xv.y);
        unsigned short h2 = f2bf(xv.z), h3 = f2bf(xv.w);
        unsigned short l0 = f2bf(xv.x - bf2f(h0)), l1 = f2bf(xv.y - bf2f(h1));
        unsigned short l2 = f2bf(xv.z - bf2f(h2)), l3 = f2bf(xv.w - bf2f(h3));
        *(uint2*)&xs_h[row][4 * k4] =
            make_uint2((unsigned)h0 | ((unsigned)h1 << 16), (unsigned)h2 | ((unsigned)h3 << 16));
        *(uint2*)&xs_l[row][4 * k4] =
            make_uint2((unsigned)l0 | ((unsigned)l1 << 16), (unsigned)l2 | ((unsigned)l3 << 16));
    }
    __syncthreads();

    float4v acc[2][4];
#pragma unroll
    for (int i = 0; i < 2; i++)
#pragma unroll
        for (int ms = 0; ms < 4; ms++) acc[i][ms] = (float4v){0.f, 0.f, 0.f, 0.f};

#pragma unroll
    for (int kc = 0; kc < 4; kc++) {
#pragma unroll
        for (int ms = 0; ms < 4; ms++) {
            short8 ah = *(short8*)&xs_h[ms * 16 + m16][kc * 32 + quad * 8];
            short8 al = *(short8*)&xs_l[ms * 16 + m16][kc * 32 + quad * 8];
#pragma unroll
            for (int i = 0; i < 2; i++) {
                int nt = i ? nt1 : nt0;
                if (nt >= NT) continue;
                acc[i][ms] = __builtin_amdgcn_mfma_f32_16x16x32_bf16(ah, bh[i][kc], acc[i][ms], 0, 0, 0);
                acc[i][ms] = __builtin_amdgcn_mfma_f32_16x16x32_bf16(al, bh[i][kc], acc[i][ms], 0, 0, 0);
                acc[i][ms] = __builtin_amdgcn_mfma_f32_16x16x32_bf16(ah, bl[i][kc], acc[i][ms], 0, 0, 0);
            }
        }
    }

#pragma unroll
    for (int i = 0; i < 2; i++) {
        int nt = i ? nt1 : nt0;
        if (nt >= NT) continue;
        int col = nt * 16 + m16;
        if (col >= OSTRIDE) continue;
#pragma unroll
        for (int ms = 0; ms < 4; ms++) {
#pragma unroll
            for (int r = 0; r < 4; r++) {
                int row = r0 + ms * 16 + quad * 4 + r;
                if (row < n) {
                    float val = (col < DOUT) ? acc[i][ms][r] * dinv[row] : 0.f;
                    Y[(size_t)row * OSTRIDE + col] = f2bf(val);
                }
            }
        }
    }
}

// ---------------- agg1: persistent, one node per wave, 4 slots x 4-in-flight ----------------
__global__ __launch_bounds__(256, 8) void k_agg_w128(
        const uint4* __restrict__ msg, const float* __restrict__ dinv,
        const int* __restrict__ rs, const int* __restrict__ deg,
        const int* __restrict__ csr, const float* __restrict__ bias,
        float* __restrict__ out, int n) {
    int lane = threadIdx.x & 63;
    int q = lane & 15;
    int slot = lane >> 4;
    int wid = blockIdx.x * 4 + (threadIdx.x >> 6);
    int nw = gridDim.x * 4;
    for (int v = wid; v < n; v += nw) {
        int start = rs[v];
        int cnt = deg[v];
        float dv = dinv[v];
        uint4 mself = msg[(size_t)v * 16 + q];
        float acc[8] = {0.f, 0.f, 0.f, 0.f, 0.f, 0.f, 0.f, 0.f};
        int i = slot;
        for (; i + 12 < cnt; i += 16) {  // 4 gathers in flight per slot
            int s0 = csr[start + i];
            int s1 = csr[start + i + 4];
            int s2 = csr[start + i + 8];
            int s3 = csr[start + i + 12];
            uint4 m0 = msg[(size_t)s0 * 16 + q];
            uint4 m1 = msg[(size_t)s1 * 16 + q];
            uint4 m2 = msg[(size_t)s2 * 16 + q];
            uint4 m3 = msg[(size_t)s3 * 16 + q];
            acc8(acc, m0);
            acc8(acc, m1);
            acc8(acc, m2);
            acc8(acc, m3);
        }
        for (; i + 4 < cnt; i += 8) {  // 2 in flight
            int s0 = csr[start + i];
            int s1 = csr[start + i + 4];
            uint4 m0 = msg[(size_t)s0 * 16 + q];
            uint4 m1 = msg[(size_t)s1 * 16 + q];
            acc8(acc, m0);
            acc8(acc, m1);
        }
        if (i < cnt) {
            int s = csr[start + i];
            uint4 m = msg[(size_t)s * 16 + q];
            acc8(acc, m);
        }
#pragma unroll
        for (int j = 0; j < 8; j++) acc[j] += __shfl_xor(acc[j], 32);
#pragma unroll
        for (int j = 0; j < 8; j++) acc[j] += __shfl_xor(acc[j], 16);
        if (slot == 0) {
            float o[8];
            o[0] = acc[0] + bf_lo(mself.x); o[1] = acc[1] + bf_hi(mself.x);
            o[2] = acc[2] + bf_lo(mself.y); o[3] = acc[3] + bf_hi(mself.y);
            o[4] = acc[4] + bf_lo(mself.z); o[5] = acc[5] + bf_hi(mself.z);
            o[6] = acc[6] + bf_lo(mself.w); o[7] = acc[7] + bf_hi(mself.w);
            float r[8];
#pragma unroll
            for (int j = 0; j < 8; j++) r[j] = fmaxf(dv * o[j] + bias[8 * q + j], 0.f);
            float4v* op = (float4v*)(out + (size_t)v * 128 + 8 * q);
            __builtin_nontemporal_store((float4v){r[0], r[1], r[2], r[3]}, op);
            __builtin_nontemporal_store((float4v){r[4], r[5], r[6], r[7]}, op + 1);
        }
    }
}

// ---------------- agg2: persistent, one node per wave, 7 slots x 9 lanes, 3-in-flight ----------------
__global__ __launch_bounds__(256, 8) void k_agg_w72(
        const uint4* __restrict__ msg, const float* __restrict__ dinv,
        const int* __restrict__ rs, const int* __restrict__ deg,
        const int* __restrict__ csr, const float* __restrict__ bias,
        float* __restrict__ out, int n) {
    int lane = threadIdx.x & 63;
    int slot = lane / 9;
    int q = lane - slot * 9;
    bool active = lane < 63;
    int wid = blockIdx.x * 4 + (threadIdx.x >> 6);
    int nw = gridDim.x * 4;
    for (int v = wid; v < n; v += nw) {
        int start = rs[v];
        int cnt = deg[v];
        float dv = dinv[v];
        float acc[8] = {0.f, 0.f, 0.f, 0.f, 0.f, 0.f, 0.f, 0.f};
        uint4 mself = make_uint4(0, 0, 0, 0);
        if (active) {
            mself = msg[(size_t)v * 9 + q];
            int i = slot;
            for (; i + 14 < cnt; i += 21) {  // 3 gathers in flight per slot
                int s0 = csr[start + i];
                int s1 = csr[start + i + 7];
                int s2 = csr[start + i + 14];
                uint4 m0 = msg[(size_t)s0 * 9 + q];
                uint4 m1 = msg[(size_t)s1 * 9 + q];
                uint4 m2 = msg[(size_t)s2 * 9 + q];
                acc8(acc, m0);
                acc8(acc, m1);
                acc8(acc, m2);
            }
            for (; i + 7 < cnt; i += 14) {
                int s0 = csr[start + i];
                int s1 = csr[start + i + 7];
                uint4 m0 = msg[(size_t)s0 * 9 + q];
                uint4 m1 = msg[(size_t)s1 * 9 + q];
                acc8(acc, m0);
                acc8(acc, m1);
            }
            if (i < cnt) {
                int s = csr[start + i];
                uint4 m = msg[(size_t)s * 9 + q];
                acc8(acc, m);
            }
        }
#pragma unroll
        for (int j = 0; j < 8; j++) {
            float t27 = __shfl(acc[j], lane + 27);
            if (lane < 27) acc[j] += t27;
        }
#pragma unroll
        for (int j = 0; j < 8; j++) {
            float t54 = __shfl(acc[j], lane + 54);
            float t9  = __shfl(acc[j], lane + 9);
            float t18 = __shfl(acc[j], lane + 18);
            if (lane < 9) acc[j] += t54 + t9 + t18;
        }
        if (lane < 9) {
            float o[8];
            o[0] = acc[0] + bf_lo(mself.x); o[1] = acc[1] + bf_hi(mself.x);
            o[2] = acc[2] + bf_lo(mself.y); o[3] = acc[3] + bf_hi(mself.y);
            o[4] = acc[4] + bf_lo(mself.z); o[5] = acc[5] + bf_hi(mself.z);
            o[6] = acc[6] + bf_lo(mself.w); o[7] = acc[7] + bf_hi(mself.w);
            float* orow = out + (size_t)v * 70 + 8 * q;
#pragma unroll
            for (int jj = 0; jj < 4; jj++) {
                int f = 8 * q + 2 * jj;
                if (f < 70) {
                    float2 st = make_float2(dv * o[2 * jj] + bias[f],
                                            dv * o[2 * jj + 1] + bias[f + 1]);
                    *(float2*)(orow + 2 * jj) = st;  // cached: L2 coalesces partial lines
                }
            }
        }
    }
}

static inline size_t alignup(size_t x) { return (x + 255) & ~(size_t)255; }

extern "C" void kernel_launch(void* const* d_in, const int* in_sizes, int n_in,
                              void* d_out, int out_size, void* d_ws, size_t ws_size,
                              hipStream_t stream) {
    const float* x = (const float*)d_in[0];
    const int* edge = (const int*)d_in[1];
    const float* W1 = (const float*)d_in[2];
    const float* b1 = (const float*)d_in[3];
    const float* W2 = (const float*)d_in[4];
    const float* b2 = (const float*)d_in[5];

    const int N = in_sizes[0] / 128;
    const int E = in_sizes[1] / 2;
    const int* src = edge;
    const int* dst = edge + E;
    const int nb = (N + 255) >> BSH;

    char* w = (char*)d_ws;
    int* deg = (int*)w;              w += alignup((size_t)N * 4);
    float* dinv = (float*)w;         w += alignup((size_t)N * 4);
    int* rs = (int*)w;               w += alignup((size_t)N * 4);
    int* bwcur = (int*)w;            w += alignup(4096);
    int* csr = (int*)w;              w += alignup((size_t)nb * BCAP * 4);
    unsigned short* msg1 = (unsigned short*)w; w += alignup((size_t)N * 128 * 2);
    unsigned short* msg2 = (unsigned short*)w; w += alignup((size_t)N * 72 * 2);
    unsigned short* w1th = (unsigned short*)w; w += alignup(128 * 128 * 2);
    unsigned short* w1tl = (unsigned short*)w; w += alignup(128 * 128 * 2);
    unsigned short* w2th = (unsigned short*)w; w += alignup(80 * 128 * 2);
    unsigned short* w2tl = (unsigned short*)w; w += alignup(80 * 128 * 2);
    float* h = (float*)w;            w += alignup((size_t)N * 128 * 4);
    unsigned long long* tmp = (unsigned long long*)h;  // aliases h (disjoint in time)

    // ---- W pre-split (one launch, both layers) ----
    k_prep_w<<<(128 * 128 + 80 * 128 + 255) / 256, 256, 0, stream>>>(
        W1, W2, w1th, w1tl, w2th, w2tl);

    // ---- CSR build: direct bucketed scatter with CAP slack (no hist, no scan) ----
    hipMemsetAsync(bwcur, 0, (size_t)nb * 4, stream);
    k_bucket_scatter<<<(E + BCHUNK - 1) / BCHUNK, 256, 0, stream>>>(src, dst, bwcur, tmp, E, nb);
    k_bucket_finalize<<<nb, 256, 0, stream>>>(tmp, bwcur, deg, dinv, rs, csr, N);

    int gblocks = (N + 63) / 64;

    // Layer 1: msg1 = bf16(dinv * (x @ W1)) [N,128] ; agg -> h [N,128] fp32 (bias+relu)
    k_gemm_mfma<128, 128, 8><<<gblocks, 256, 0, stream>>>(x, w1th, w1tl, dinv, msg1, N);
    k_agg_w128<<<2048, 256, 0, stream>>>((const uint4*)msg1, dinv, rs, deg, csr, b1, h, N);

    // Layer 2: msg2 = bf16(dinv * (h @ W2)) [N,72 pad] ; agg -> d_out [N,70] (bias)
    k_gemm_mfma<70, 72, 5><<<gblocks, 256, 0, stream>>>(h, w2th, w2tl, dinv, msg2, N);
    k_agg_w72<<<2048, 256, 0, stream>>>((const uint4*)msg2, dinv, rs, deg, csr, b2,
                                        (float*)d_out, N);
}

// Round 9
// 335.121 us; speedup vs baseline: 1.4164x; 1.0212x over previous
//
#include <hip/hip_runtime.h>
#include <hip/hip_bf16.h>

// GCN 2-layer. msg[s] = dinv[s] * (x@W)[s] stored in bf16 (dinv folded at GEMM epilogue).
// out[v] = dinv[v] * (sum_{e:dst=v} msg[src] + msg[v]) + b ; layer1 relu.
// GEMMs: MFMA 16x16x32 bf16, 2-term split (~fp32 accuracy), x tile in LDS.
// Aggregation: persistent grid-stride, one node per wave, shuffle reduce at END only.
// --- Session ledger ---
// R7: never fuse the latency-bound gather into an LDS-heavy MFMA kernel (occupancy).
// R8: nt stores only on >=64B-contiguous sectors (8B scattered nt = 4x write amp).
// R9: flat agg is TRAFFIC-bound (deeper MLP: zero delta) at ~3.8TB/s L2-miss service.
// R10: blockIdx%8->XCD round-robin pinning real (FETCH 193->46MB) but 8 chunk-visits
//     x wave-shuffle-reduce = DS-pipe bound (383us).
// R11: chunked per-lane serial walk = csr transaction + divergence bound (117us).
// R13: device-wide-atomic csr fill = 16x write amp on random 4B stores (120us).
// R14: half-split gave ZERO fetch reduction -> per-XCD hit rate only improves when
//     pinned set fits 4MB L2; all such structures lose more on execution than saved.
// R12/R15 (base, 342us): flat aggs at measured ceiling (65us, 193MB, 3.8TB/s,
//     bit-stable) + 2-kernel bucketed CSR build + merged prep_w + float4 nt staging.
// R16: invisible-region trims only: (a) bwcur clear folded into prep_w (-1 dispatch),
//     (b) BCHUNK 8192->4096: scatter 196->391 blocks (was <1 block/CU, 3 serial
//     passes on an idle machine); per-bucket runs 168->84B still >= one line so
//     R13-style write amp stays bounded.

#define BSH 8
#define BCHUNK 4096
#define BCAP 8192  // tmp/csr slots per bucket (mean 4096, 64-sigma slack)

typedef __attribute__((ext_vector_type(8))) short short8;
typedef __attribute__((ext_vector_type(4))) float float4v;
typedef __attribute__((ext_vector_type(2))) float float2v;

__device__ __forceinline__ float bf_lo(unsigned u) { return __uint_as_float(u << 16); }
__device__ __forceinline__ float bf_hi(unsigned u) { return __uint_as_float(u & 0xffff0000u); }
__device__ __forceinline__ float bf2f(unsigned short h) {
    return __uint_as_float((unsigned)h << 16);
}
__device__ __forceinline__ unsigned short f2bf(float f) {
    unsigned u = __float_as_uint(f);
    u += 0x7fff + ((u >> 16) & 1);  // round-to-nearest-even
    return (unsigned short)(u >> 16);
}
__device__ __forceinline__ void acc8(float* acc, uint4 m) {
    acc[0] += bf_lo(m.x); acc[1] += bf_hi(m.x);
    acc[2] += bf_lo(m.y); acc[3] += bf_hi(m.y);
    acc[4] += bf_lo(m.z); acc[5] += bf_hi(m.z);
    acc[6] += bf_lo(m.w); acc[7] += bf_hi(m.w);
}

// ---------------- CSR build (2 kernels, clustered writes) ----------------
__global__ void k_bucket_scatter(const int* __restrict__ src, const int* __restrict__ dst,
                                 int* __restrict__ bwcur,
                                 unsigned long long* __restrict__ tmp, int E, int nb) {
    __shared__ int lh[512];
    __shared__ int lb[512];
    int t = threadIdx.x;
    for (int j = t; j < nb; j += 256) lh[j] = 0;
    __syncthreads();
    int e0 = blockIdx.x * BCHUNK;
    int e1 = min(E, e0 + BCHUNK);
    for (int e = e0 + t; e < e1; e += 256) atomicAdd(&lh[dst[e] >> BSH], 1);
    __syncthreads();
    for (int j = t; j < nb; j += 256) {
        int c = lh[j];
        lb[j] = c ? atomicAdd(&bwcur[j], c) : 0;
        lh[j] = 0;
    }
    __syncthreads();
    for (int e = e0 + t; e < e1; e += 256) {
        int d = dst[e];
        int b = d >> BSH;
        int o = atomicAdd(&lh[b], 1);
        int pos = lb[b] + o;
        if (pos < BCAP)  // memory-safe clamp
            tmp[(size_t)b * BCAP + pos] =
                ((unsigned long long)(unsigned)d << 32) | (unsigned)src[e];
    }
}

__global__ void k_bucket_finalize(const unsigned long long* __restrict__ tmp,
                                  const int* __restrict__ bwcur,
                                  int* __restrict__ deg, float* __restrict__ dinv,
                                  int* __restrict__ rs, int* __restrict__ csr, int N) {
    __shared__ int cnt[256];
    __shared__ int sc[256];
    int b = blockIdx.x;
    int t = threadIdx.x;
    int e0 = b * BCAP;
    int e1 = e0 + min(bwcur[b], BCAP);
    cnt[t] = 0;
    __syncthreads();
    for (int e = e0 + t; e < e1; e += 256) {
        int d = (int)(tmp[e] >> 32);
        atomicAdd(&cnt[d & 255], 1);
    }
    __syncthreads();
    int c = cnt[t];
    sc[t] = c;
    __syncthreads();
    for (int off = 1; off < 256; off <<= 1) {
        int add = (t >= off) ? sc[t - off] : 0;
        __syncthreads();
        sc[t] += add;
        __syncthreads();
    }
    int excl = sc[t] - c;
    __syncthreads();
    sc[t] = excl;
    int node = (b << BSH) + t;
    if (node < N) {
        deg[node] = c;
        dinv[node] = rsqrtf((float)(c + 1));
        rs[node] = e0 + excl;
    }
    cnt[t] = 0;
    __syncthreads();
    for (int e = e0 + t; e < e1; e += 256) {
        unsigned long long p = tmp[e];
        int j = ((int)(p >> 32)) & 255;
        int o = atomicAdd(&cnt[j], 1);
        csr[e0 + sc[j] + o] = (int)(p & 0xffffffffu);
    }
}

// ---------------- W pre-split (both layers) + bwcur clear, one launch ----------------
__global__ void k_prep_w(const float* __restrict__ W1, const float* __restrict__ W2,
                         unsigned short* __restrict__ w1th, unsigned short* __restrict__ w1tl,
                         unsigned short* __restrict__ w2th, unsigned short* __restrict__ w2tl,
                         int* __restrict__ bwcur) {
    if (blockIdx.x >= 104) {  // tail blocks: clear bucket cursors (nb <= 512)
        int idx = (blockIdx.x - 104) * 256 + threadIdx.x;
        if (idx < 512) bwcur[idx] = 0;
        return;
    }
    int i = blockIdx.x * blockDim.x + threadIdx.x;
    if (i < 128 * 128) {
        int col = i % 128, k = i / 128;
        float w = W1[k * 128 + col];
        unsigned short h = f2bf(w);
        w1th[(size_t)col * 128 + k] = h;
        w1tl[(size_t)col * 128 + k] = f2bf(w - bf2f(h));
    } else if (i < 128 * 128 + 80 * 128) {
        int j = i - 128 * 128;
        int col = j % 80, k = j / 80;
        float w = (col < 70) ? W2[k * 70 + col] : 0.f;
        unsigned short h = f2bf(w);
        w2th[(size_t)col * 128 + k] = h;
        w2tl[(size_t)col * 128 + k] = f2bf(w - bf2f(h));
    }
}

// ---------------- MFMA GEMM (split-bf16, ~fp32 accuracy) ----------------
// Y[r,c] = bf16(dinv[r] * (X@W)[r,c]). Block: 4 waves, 64 rows, K=128.
// B frags loaded as 16B vectors from pre-split Wt. X staged via float4 nt loads.
template <int DOUT, int OSTRIDE, int NT>
__global__ __launch_bounds__(256, 3) void k_gemm_mfma(
        const float* __restrict__ X, const unsigned short* __restrict__ Wth,
        const unsigned short* __restrict__ Wtl,
        const float* __restrict__ dinv, unsigned short* __restrict__ Y, int n) {
    __shared__ short xs_h[64][136];
    __shared__ short xs_l[64][136];
    int t = threadIdx.x;
    int lane = t & 63, wave = t >> 6;
    int m16 = lane & 15, quad = lane >> 4;
    int r0 = blockIdx.x * 64;

    short8 bh[2][4], bl[2][4];
    int nt0 = wave, nt1 = wave + 4;
#pragma unroll
    for (int i = 0; i < 2; i++) {
        int nt = i ? nt1 : nt0;
        if (nt >= NT) continue;
        int col = nt * 16 + m16;  // < NT*16 <= padded Wt cols
#pragma unroll
        for (int kc = 0; kc < 4; kc++) {
            bh[i][kc] = *(const short8*)&Wth[(size_t)col * 128 + kc * 32 + quad * 8];
            bl[i][kc] = *(const short8*)&Wtl[(size_t)col * 128 + kc * 32 + quad * 8];
        }
    }

    for (int p = t; p < 64 * 32; p += 256) {
        int row = p >> 5;
        int k4 = p & 31;
        int gr = r0 + row;
        if (gr >= n) gr = n - 1;
        float4v xv = __builtin_nontemporal_load(
            (const float4v*)(X + (size_t)gr * 128 + 4 * k4));
        unsigned short h0 = f2bf(xv.x), h1 = f2bf(xv.y);
        unsigned short h2 = f2bf(xv.z), h3 = f2bf(xv.w);
        unsigned short l0 = f2bf(xv.x - bf2f(h0)), l1 = f2bf(xv.y - bf2f(h1));
        unsigned short l2 = f2bf(xv.z - bf2f(h2)), l3 = f2bf(xv.w - bf2f(h3));
        *(uint2*)&xs_h[row][4 * k4] =
            make_uint2((unsigned)h0 | ((unsigned)h1 << 16), (unsigned)h2 | ((unsigned)h3 << 16));
        *(uint2*)&xs_l[row][4 * k4] =
            make_uint2((unsigned)l0 | ((unsigned)l1 << 16), (unsigned)l2 | ((unsigned)l3 << 16));
    }
    __syncthreads();

    float4v acc[2][4];
#pragma unroll
    for (int i = 0; i < 2; i++)
#pragma unroll
        for (int ms = 0; ms < 4; ms++) acc[i][ms] = (float4v){0.f, 0.f, 0.f, 0.f};

#pragma unroll
    for (int kc = 0; kc < 4; kc++) {
#pragma unroll
        for (int ms = 0; ms < 4; ms++) {
            short8 ah = *(short8*)&xs_h[ms * 16 + m16][kc * 32 + quad * 8];
            short8 al = *(short8*)&xs_l[ms * 16 + m16][kc * 32 + quad * 8];
#pragma unroll
            for (int i = 0; i < 2; i++) {
                int nt = i ? nt1 : nt0;
                if (nt >= NT) continue;
                acc[i][ms] = __builtin_amdgcn_mfma_f32_16x16x32_bf16(ah, bh[i][kc], acc[i][ms], 0, 0, 0);
                acc[i][ms] = __builtin_amdgcn_mfma_f32_16x16x32_bf16(al, bh[i][kc], acc[i][ms], 0, 0, 0);
                acc[i][ms] = __builtin_amdgcn_mfma_f32_16x16x32_bf16(ah, bl[i][kc], acc[i][ms], 0, 0, 0);
            }
        }
    }

#pragma unroll
    for (int i = 0; i < 2; i++) {
        int nt = i ? nt1 : nt0;
        if (nt >= NT) continue;
        int col = nt * 16 + m16;
        if (col >= OSTRIDE) continue;
#pragma unroll
        for (int ms = 0; ms < 4; ms++) {
#pragma unroll
            for (int r = 0; r < 4; r++) {
                int row = r0 + ms * 16 + quad * 4 + r;
                if (row < n) {
                    float val = (col < DOUT) ? acc[i][ms][r] * dinv[row] : 0.f;
                    Y[(size_t)row * OSTRIDE + col] = f2bf(val);
                }
            }
        }
    }
}

// ---------------- agg1: persistent, one node per wave, 4 slots x 4-in-flight ----------------
__global__ __launch_bounds__(256, 8) void k_agg_w128(
        const uint4* __restrict__ msg, const float* __restrict__ dinv,
        const int* __restrict__ rs, const int* __restrict__ deg,
        const int* __restrict__ csr, const float* __restrict__ bias,
        float* __restrict__ out, int n) {
    int lane = threadIdx.x & 63;
    int q = lane & 15;
    int slot = lane >> 4;
    int wid = blockIdx.x * 4 + (threadIdx.x >> 6);
    int nw = gridDim.x * 4;
    for (int v = wid; v < n; v += nw) {
        int start = rs[v];
        int cnt = deg[v];
        float dv = dinv[v];
        uint4 mself = msg[(size_t)v * 16 + q];
        float acc[8] = {0.f, 0.f, 0.f, 0.f, 0.f, 0.f, 0.f, 0.f};
        int i = slot;
        for (; i + 12 < cnt; i += 16) {  // 4 gathers in flight per slot
            int s0 = csr[start + i];
            int s1 = csr[start + i + 4];
            int s2 = csr[start + i + 8];
            int s3 = csr[start + i + 12];
            uint4 m0 = msg[(size_t)s0 * 16 + q];
            uint4 m1 = msg[(size_t)s1 * 16 + q];
            uint4 m2 = msg[(size_t)s2 * 16 + q];
            uint4 m3 = msg[(size_t)s3 * 16 + q];
            acc8(acc, m0);
            acc8(acc, m1);
            acc8(acc, m2);
            acc8(acc, m3);
        }
        for (; i + 4 < cnt; i += 8) {  // 2 in flight
            int s0 = csr[start + i];
            int s1 = csr[start + i + 4];
            uint4 m0 = msg[(size_t)s0 * 16 + q];
            uint4 m1 = msg[(size_t)s1 * 16 + q];
            acc8(acc, m0);
            acc8(acc, m1);
        }
        if (i < cnt) {
            int s = csr[start + i];
            uint4 m = msg[(size_t)s * 16 + q];
            acc8(acc, m);
        }
#pragma unroll
        for (int j = 0; j < 8; j++) acc[j] += __shfl_xor(acc[j], 32);
#pragma unroll
        for (int j = 0; j < 8; j++) acc[j] += __shfl_xor(acc[j], 16);
        if (slot == 0) {
            float o[8];
            o[0] = acc[0] + bf_lo(mself.x); o[1] = acc[1] + bf_hi(mself.x);
            o[2] = acc[2] + bf_lo(mself.y); o[3] = acc[3] + bf_hi(mself.y);
            o[4] = acc[4] + bf_lo(mself.z); o[5] = acc[5] + bf_hi(mself.z);
            o[6] = acc[6] + bf_lo(mself.w); o[7] = acc[7] + bf_hi(mself.w);
            float r[8];
#pragma unroll
            for (int j = 0; j < 8; j++) r[j] = fmaxf(dv * o[j] + bias[8 * q + j], 0.f);
            float4v* op = (float4v*)(out + (size_t)v * 128 + 8 * q);
            __builtin_nontemporal_store((float4v){r[0], r[1], r[2], r[3]}, op);
            __builtin_nontemporal_store((float4v){r[4], r[5], r[6], r[7]}, op + 1);
        }
    }
}

// ---------------- agg2: persistent, one node per wave, 7 slots x 9 lanes, 3-in-flight ----------------
__global__ __launch_bounds__(256, 8) void k_agg_w72(
        const uint4* __restrict__ msg, const float* __restrict__ dinv,
        const int* __restrict__ rs, const int* __restrict__ deg,
        const int* __restrict__ csr, const float* __restrict__ bias,
        float* __restrict__ out, int n) {
    int lane = threadIdx.x & 63;
    int slot = lane / 9;
    int q = lane - slot * 9;
    bool active = lane < 63;
    int wid = blockIdx.x * 4 + (threadIdx.x >> 6);
    int nw = gridDim.x * 4;
    for (int v = wid; v < n; v += nw) {
        int start = rs[v];
        int cnt = deg[v];
        float dv = dinv[v];
        float acc[8] = {0.f, 0.f, 0.f, 0.f, 0.f, 0.f, 0.f, 0.f};
        uint4 mself = make_uint4(0, 0, 0, 0);
        if (active) {
            mself = msg[(size_t)v * 9 + q];
            int i = slot;
            for (; i + 14 < cnt; i += 21) {  // 3 gathers in flight per slot
                int s0 = csr[start + i];
                int s1 = csr[start + i + 7];
                int s2 = csr[start + i + 14];
                uint4 m0 = msg[(size_t)s0 * 9 + q];
                uint4 m1 = msg[(size_t)s1 * 9 + q];
                uint4 m2 = msg[(size_t)s2 * 9 + q];
                acc8(acc, m0);
                acc8(acc, m1);
                acc8(acc, m2);
            }
            for (; i + 7 < cnt; i += 14) {
                int s0 = csr[start + i];
                int s1 = csr[start + i + 7];
                uint4 m0 = msg[(size_t)s0 * 9 + q];
                uint4 m1 = msg[(size_t)s1 * 9 + q];
                acc8(acc, m0);
                acc8(acc, m1);
            }
            if (i < cnt) {
                int s = csr[start + i];
                uint4 m = msg[(size_t)s * 9 + q];
                acc8(acc, m);
            }
        }
#pragma unroll
        for (int j = 0; j < 8; j++) {
            float t27 = __shfl(acc[j], lane + 27);
            if (lane < 27) acc[j] += t27;
        }
#pragma unroll
        for (int j = 0; j < 8; j++) {
            float t54 = __shfl(acc[j], lane + 54);
            float t9  = __shfl(acc[j], lane + 9);
            float t18 = __shfl(acc[j], lane + 18);
            if (lane < 9) acc[j] += t54 + t9 + t18;
        }
        if (lane < 9) {
            float o[8];
            o[0] = acc[0] + bf_lo(mself.x); o[1] = acc[1] + bf_hi(mself.x);
            o[2] = acc[2] + bf_lo(mself.y); o[3] = acc[3] + bf_hi(mself.y);
            o[4] = acc[4] + bf_lo(mself.z); o[5] = acc[5] + bf_hi(mself.z);
            o[6] = acc[6] + bf_lo(mself.w); o[7] = acc[7] + bf_hi(mself.w);
            float* orow = out + (size_t)v * 70 + 8 * q;
#pragma unroll
            for (int jj = 0; jj < 4; jj++) {
                int f = 8 * q + 2 * jj;
                if (f < 70) {
                    float2 st = make_float2(dv * o[2 * jj] + bias[f],
                                            dv * o[2 * jj + 1] + bias[f + 1]);
                    *(float2*)(orow + 2 * jj) = st;  // cached: L2 coalesces partial lines
                }
            }
        }
    }
}

static inline size_t alignup(size_t x) { return (x + 255) & ~(size_t)255; }

extern "C" void kernel_launch(void* const* d_in, const int* in_sizes, int n_in,
                              void* d_out, int out_size, void* d_ws, size_t ws_size,
                              hipStream_t stream) {
    const float* x = (const float*)d_in[0];
    const int* edge = (const int*)d_in[1];
    const float* W1 = (const float*)d_in[2];
    const float* b1 = (const float*)d_in[3];
    const float* W2 = (const float*)d_in[4];
    const float* b2 = (const float*)d_in[5];

    const int N = in_sizes[0] / 128;
    const int E = in_sizes[1] / 2;
    const int* src = edge;
    const int* dst = edge + E;
    const int nb = (N + 255) >> BSH;

    char* w = (char*)d_ws;
    int* deg = (int*)w;              w += alignup((size_t)N * 4);
    float* dinv = (float*)w;         w += alignup((size_t)N * 4);
    int* rs = (int*)w;               w += alignup((size_t)N * 4);
    int* bwcur = (int*)w;            w += alignup(4096);
    int* csr = (int*)w;              w += alignup((size_t)nb * BCAP * 4);
    unsigned short* msg1 = (unsigned short*)w; w += alignup((size_t)N * 128 * 2);
    unsigned short* msg2 = (unsigned short*)w; w += alignup((size_t)N * 72 * 2);
    unsigned short* w1th = (unsigned short*)w; w += alignup(128 * 128 * 2);
    unsigned short* w1tl = (unsigned short*)w; w += alignup(128 * 128 * 2);
    unsigned short* w2th = (unsigned short*)w; w += alignup(80 * 128 * 2);
    unsigned short* w2tl = (unsigned short*)w; w += alignup(80 * 128 * 2);
    float* h = (float*)w;            w += alignup((size_t)N * 128 * 4);
    unsigned long long* tmp = (unsigned long long*)h;  // aliases h (disjoint in time)

    // ---- W pre-split + bwcur clear (one launch; precedes scatter on-stream) ----
    k_prep_w<<<104 + 2, 256, 0, stream>>>(W1, W2, w1th, w1tl, w2th, w2tl, bwcur);

    // ---- CSR build: direct bucketed scatter with CAP slack ----
    k_bucket_scatter<<<(E + BCHUNK - 1) / BCHUNK, 256, 0, stream>>>(src, dst, bwcur, tmp, E, nb);
    k_bucket_finalize<<<nb, 256, 0, stream>>>(tmp, bwcur, deg, dinv, rs, csr, N);

    int gblocks = (N + 63) / 64;

    // Layer 1: msg1 = bf16(dinv * (x @ W1)) [N,128] ; agg -> h [N,128] fp32 (bias+relu)
    k_gemm_mfma<128, 128, 8><<<gblocks, 256, 0, stream>>>(x, w1th, w1tl, dinv, msg1, N);
    k_agg_w128<<<2048, 256, 0, stream>>>((const uint4*)msg1, dinv, rs, deg, csr, b1, h, N);

    // Layer 2: msg2 = bf16(dinv * (h @ W2)) [N,72 pad] ; agg -> d_out [N,70] (bias)
    k_gemm_mfma<70, 72, 5><<<gblocks, 256, 0, stream>>>(h, w2th, w2tl, dinv, msg2, N);
    k_agg_w72<<<2048, 256, 0, stream>>>((const uint4*)msg2, dinv, rs, deg, csr, b2,
                                        (float*)d_out, N);
}

// Round 10
// 330.698 us; speedup vs baseline: 1.4353x; 1.0134x over previous
//
#include <hip/hip_runtime.h>
#include <hip/hip_bf16.h>

// GCN 2-layer. msg[s] = dinv[s] * (x@W)[s] stored in bf16 (dinv folded at GEMM epilogue).
// out[v] = dinv[v] * (sum_{e:dst=v} msg[src] + msg[v]) + b ; layer1 relu.
// GEMMs: MFMA 16x16x32 bf16, 2-term split (~fp32 accuracy), x tile in LDS.
// Aggregation: persistent grid-stride, one node per wave, shuffle reduce at END only.
// --- Session ledger ---
// R7: never fuse the latency-bound gather into an LDS-heavy MFMA kernel (occupancy).
// R8: nt stores only on >=64B-contiguous sectors (8B scattered nt = 4x write amp).
// R9: flat agg is TRAFFIC-bound (deeper MLP: zero delta) at ~3.8TB/s L2-miss service.
// R10: blockIdx%8->XCD round-robin pinning real (FETCH 193->46MB) but 8 chunk-visits
//     x wave-shuffle-reduce = DS-pipe bound (383us).
// R11: chunked per-lane serial walk = csr transaction + divergence bound (117us).
// R13: device-wide-atomic csr fill = 16x write amp on random 4B stores (120us).
// R14: half-split gave ZERO fetch reduction -> per-XCD hit rate only improves when
//     pinned set fits 4MB L2; all such structures lose more on execution than saved.
// R12/R15: flat aggs at measured ceiling (65us, 193MB, 3.8TB/s, bit-stable).
// R16 (335us): bwcur clear folded into prep_w; BCHUNK 8192->4096 (scatter 196->391
//     blocks). Matched prediction - build latency is real.
// R17: build kernels 256->512 threads: serial passes halve (16->8 iters) at identical
//     block count and write clustering (no R13 amp risk). Pure latency cut on the
//     two ~1.5-block/CU under-occupied kernels.

#define BSH 8
#define BCHUNK 4096
#define BCAP 8192  // tmp/csr slots per bucket (mean 4096, 64-sigma slack)

typedef __attribute__((ext_vector_type(8))) short short8;
typedef __attribute__((ext_vector_type(4))) float float4v;
typedef __attribute__((ext_vector_type(2))) float float2v;

__device__ __forceinline__ float bf_lo(unsigned u) { return __uint_as_float(u << 16); }
__device__ __forceinline__ float bf_hi(unsigned u) { return __uint_as_float(u & 0xffff0000u); }
__device__ __forceinline__ float bf2f(unsigned short h) {
    return __uint_as_float((unsigned)h << 16);
}
__device__ __forceinline__ unsigned short f2bf(float f) {
    unsigned u = __float_as_uint(f);
    u += 0x7fff + ((u >> 16) & 1);  // round-to-nearest-even
    return (unsigned short)(u >> 16);
}
__device__ __forceinline__ void acc8(float* acc, uint4 m) {
    acc[0] += bf_lo(m.x); acc[1] += bf_hi(m.x);
    acc[2] += bf_lo(m.y); acc[3] += bf_hi(m.y);
    acc[4] += bf_lo(m.z); acc[5] += bf_hi(m.z);
    acc[6] += bf_lo(m.w); acc[7] += bf_hi(m.w);
}

// ---------------- CSR build (2 kernels, 512 threads, clustered writes) ----------------
__global__ __launch_bounds__(512) void k_bucket_scatter(
        const int* __restrict__ src, const int* __restrict__ dst,
        int* __restrict__ bwcur, unsigned long long* __restrict__ tmp, int E, int nb) {
    __shared__ int lh[512];
    __shared__ int lb[512];
    int t = threadIdx.x;
    for (int j = t; j < nb; j += 512) lh[j] = 0;
    __syncthreads();
    int e0 = blockIdx.x * BCHUNK;
    int e1 = min(E, e0 + BCHUNK);
    for (int e = e0 + t; e < e1; e += 512) atomicAdd(&lh[dst[e] >> BSH], 1);
    __syncthreads();
    for (int j = t; j < nb; j += 512) {
        int c = lh[j];
        lb[j] = c ? atomicAdd(&bwcur[j], c) : 0;
        lh[j] = 0;
    }
    __syncthreads();
    for (int e = e0 + t; e < e1; e += 512) {
        int d = dst[e];
        int b = d >> BSH;
        int o = atomicAdd(&lh[b], 1);
        int pos = lb[b] + o;
        if (pos < BCAP)  // memory-safe clamp
            tmp[(size_t)b * BCAP + pos] =
                ((unsigned long long)(unsigned)d << 32) | (unsigned)src[e];
    }
}

__global__ __launch_bounds__(512) void k_bucket_finalize(
        const unsigned long long* __restrict__ tmp, const int* __restrict__ bwcur,
        int* __restrict__ deg, float* __restrict__ dinv,
        int* __restrict__ rs, int* __restrict__ csr, int N) {
    __shared__ int cnt[256];
    __shared__ int sc[256];
    int b = blockIdx.x;
    int t = threadIdx.x;
    int e0 = b * BCAP;
    int e1 = e0 + min(bwcur[b], BCAP);
    if (t < 256) cnt[t] = 0;
    __syncthreads();
    for (int e = e0 + t; e < e1; e += 512) {
        int d = (int)(tmp[e] >> 32);
        atomicAdd(&cnt[d & 255], 1);
    }
    __syncthreads();
    int c = (t < 256) ? cnt[t] : 0;
    if (t < 256) sc[t] = c;
    __syncthreads();
    for (int off = 1; off < 256; off <<= 1) {
        int add = (t >= off && t < 256) ? sc[t - off] : 0;
        __syncthreads();
        if (t < 256) sc[t] += add;
        __syncthreads();
    }
    int excl = (t < 256) ? (sc[t] - c) : 0;
    __syncthreads();
    if (t < 256) sc[t] = excl;
    int node = (b << BSH) + t;
    if (t < 256 && node < N) {
        deg[node] = c;
        dinv[node] = rsqrtf((float)(c + 1));
        rs[node] = e0 + excl;
    }
    if (t < 256) cnt[t] = 0;
    __syncthreads();
    for (int e = e0 + t; e < e1; e += 512) {
        unsigned long long p = tmp[e];
        int j = ((int)(p >> 32)) & 255;
        int o = atomicAdd(&cnt[j], 1);
        csr[e0 + sc[j] + o] = (int)(p & 0xffffffffu);
    }
}

// ---------------- W pre-split (both layers) + bwcur clear, one launch ----------------
__global__ void k_prep_w(const float* __restrict__ W1, const float* __restrict__ W2,
                         unsigned short* __restrict__ w1th, unsigned short* __restrict__ w1tl,
                         unsigned short* __restrict__ w2th, unsigned short* __restrict__ w2tl,
                         int* __restrict__ bwcur) {
    if (blockIdx.x >= 104) {  // tail blocks: clear bucket cursors (nb <= 512)
        int idx = (blockIdx.x - 104) * 256 + threadIdx.x;
        if (idx < 512) bwcur[idx] = 0;
        return;
    }
    int i = blockIdx.x * blockDim.x + threadIdx.x;
    if (i < 128 * 128) {
        int col = i % 128, k = i / 128;
        float w = W1[k * 128 + col];
        unsigned short h = f2bf(w);
        w1th[(size_t)col * 128 + k] = h;
        w1tl[(size_t)col * 128 + k] = f2bf(w - bf2f(h));
    } else if (i < 128 * 128 + 80 * 128) {
        int j = i - 128 * 128;
        int col = j % 80, k = j / 80;
        float w = (col < 70) ? W2[k * 70 + col] : 0.f;
        unsigned short h = f2bf(w);
        w2th[(size_t)col * 128 + k] = h;
        w2tl[(size_t)col * 128 + k] = f2bf(w - bf2f(h));
    }
}

// ---------------- MFMA GEMM (split-bf16, ~fp32 accuracy) ----------------
// Y[r,c] = bf16(dinv[r] * (X@W)[r,c]). Block: 4 waves, 64 rows, K=128.
// B frags loaded as 16B vectors from pre-split Wt. X staged via float4 nt loads.
template <int DOUT, int OSTRIDE, int NT>
__global__ __launch_bounds__(256, 3) void k_gemm_mfma(
        const float* __restrict__ X, const unsigned short* __restrict__ Wth,
        const unsigned short* __restrict__ Wtl,
        const float* __restrict__ dinv, unsigned short* __restrict__ Y, int n) {
    __shared__ short xs_h[64][136];
    __shared__ short xs_l[64][136];
    int t = threadIdx.x;
    int lane = t & 63, wave = t >> 6;
    int m16 = lane & 15, quad = lane >> 4;
    int r0 = blockIdx.x * 64;

    short8 bh[2][4], bl[2][4];
    int nt0 = wave, nt1 = wave + 4;
#pragma unroll
    for (int i = 0; i < 2; i++) {
        int nt = i ? nt1 : nt0;
        if (nt >= NT) continue;
        int col = nt * 16 + m16;  // < NT*16 <= padded Wt cols
#pragma unroll
        for (int kc = 0; kc < 4; kc++) {
            bh[i][kc] = *(const short8*)&Wth[(size_t)col * 128 + kc * 32 + quad * 8];
            bl[i][kc] = *(const short8*)&Wtl[(size_t)col * 128 + kc * 32 + quad * 8];
        }
    }

    for (int p = t; p < 64 * 32; p += 256) {
        int row = p >> 5;
        int k4 = p & 31;
        int gr = r0 + row;
        if (gr >= n) gr = n - 1;
        float4v xv = __builtin_nontemporal_load(
            (const float4v*)(X + (size_t)gr * 128 + 4 * k4));
        unsigned short h0 = f2bf(xv.x), h1 = f2bf(xv.y);
        unsigned short h2 = f2bf(xv.z), h3 = f2bf(xv.w);
        unsigned short l0 = f2bf(xv.x - bf2f(h0)), l1 = f2bf(xv.y - bf2f(h1));
        unsigned short l2 = f2bf(xv.z - bf2f(h2)), l3 = f2bf(xv.w - bf2f(h3));
        *(uint2*)&xs_h[row][4 * k4] =
            make_uint2((unsigned)h0 | ((unsigned)h1 << 16), (unsigned)h2 | ((unsigned)h3 << 16));
        *(uint2*)&xs_l[row][4 * k4] =
            make_uint2((unsigned)l0 | ((unsigned)l1 << 16), (unsigned)l2 | ((unsigned)l3 << 16));
    }
    __syncthreads();

    float4v acc[2][4];
#pragma unroll
    for (int i = 0; i < 2; i++)
#pragma unroll
        for (int ms = 0; ms < 4; ms++) acc[i][ms] = (float4v){0.f, 0.f, 0.f, 0.f};

#pragma unroll
    for (int kc = 0; kc < 4; kc++) {
#pragma unroll
        for (int ms = 0; ms < 4; ms++) {
            short8 ah = *(short8*)&xs_h[ms * 16 + m16][kc * 32 + quad * 8];
            short8 al = *(short8*)&xs_l[ms * 16 + m16][kc * 32 + quad * 8];
#pragma unroll
            for (int i = 0; i < 2; i++) {
                int nt = i ? nt1 : nt0;
                if (nt >= NT) continue;
                acc[i][ms] = __builtin_amdgcn_mfma_f32_16x16x32_bf16(ah, bh[i][kc], acc[i][ms], 0, 0, 0);
                acc[i][ms] = __builtin_amdgcn_mfma_f32_16x16x32_bf16(al, bh[i][kc], acc[i][ms], 0, 0, 0);
                acc[i][ms] = __builtin_amdgcn_mfma_f32_16x16x32_bf16(ah, bl[i][kc], acc[i][ms], 0, 0, 0);
            }
        }
    }

#pragma unroll
    for (int i = 0; i < 2; i++) {
        int nt = i ? nt1 : nt0;
        if (nt >= NT) continue;
        int col = nt * 16 + m16;
        if (col >= OSTRIDE) continue;
#pragma unroll
        for (int ms = 0; ms < 4; ms++) {
#pragma unroll
            for (int r = 0; r < 4; r++) {
                int row = r0 + ms * 16 + quad * 4 + r;
                if (row < n) {
                    float val = (col < DOUT) ? acc[i][ms][r] * dinv[row] : 0.f;
                    Y[(size_t)row * OSTRIDE + col] = f2bf(val);
                }
            }
        }
    }
}

// ---------------- agg1: persistent, one node per wave, 4 slots x 4-in-flight ----------------
__global__ __launch_bounds__(256, 8) void k_agg_w128(
        const uint4* __restrict__ msg, const float* __restrict__ dinv,
        const int* __restrict__ rs, const int* __restrict__ deg,
        const int* __restrict__ csr, const float* __restrict__ bias,
        float* __restrict__ out, int n) {
    int lane = threadIdx.x & 63;
    int q = lane & 15;
    int slot = lane >> 4;
    int wid = blockIdx.x * 4 + (threadIdx.x >> 6);
    int nw = gridDim.x * 4;
    for (int v = wid; v < n; v += nw) {
        int start = rs[v];
        int cnt = deg[v];
        float dv = dinv[v];
        uint4 mself = msg[(size_t)v * 16 + q];
        float acc[8] = {0.f, 0.f, 0.f, 0.f, 0.f, 0.f, 0.f, 0.f};
        int i = slot;
        for (; i + 12 < cnt; i += 16) {  // 4 gathers in flight per slot
            int s0 = csr[start + i];
            int s1 = csr[start + i + 4];
            int s2 = csr[start + i + 8];
            int s3 = csr[start + i + 12];
            uint4 m0 = msg[(size_t)s0 * 16 + q];
            uint4 m1 = msg[(size_t)s1 * 16 + q];
            uint4 m2 = msg[(size_t)s2 * 16 + q];
            uint4 m3 = msg[(size_t)s3 * 16 + q];
            acc8(acc, m0);
            acc8(acc, m1);
            acc8(acc, m2);
            acc8(acc, m3);
        }
        for (; i + 4 < cnt; i += 8) {  // 2 in flight
            int s0 = csr[start + i];
            int s1 = csr[start + i + 4];
            uint4 m0 = msg[(size_t)s0 * 16 + q];
            uint4 m1 = msg[(size_t)s1 * 16 + q];
            acc8(acc, m0);
            acc8(acc, m1);
        }
        if (i < cnt) {
            int s = csr[start + i];
            uint4 m = msg[(size_t)s * 16 + q];
            acc8(acc, m);
        }
#pragma unroll
        for (int j = 0; j < 8; j++) acc[j] += __shfl_xor(acc[j], 32);
#pragma unroll
        for (int j = 0; j < 8; j++) acc[j] += __shfl_xor(acc[j], 16);
        if (slot == 0) {
            float o[8];
            o[0] = acc[0] + bf_lo(mself.x); o[1] = acc[1] + bf_hi(mself.x);
            o[2] = acc[2] + bf_lo(mself.y); o[3] = acc[3] + bf_hi(mself.y);
            o[4] = acc[4] + bf_lo(mself.z); o[5] = acc[5] + bf_hi(mself.z);
            o[6] = acc[6] + bf_lo(mself.w); o[7] = acc[7] + bf_hi(mself.w);
            float r[8];
#pragma unroll
            for (int j = 0; j < 8; j++) r[j] = fmaxf(dv * o[j] + bias[8 * q + j], 0.f);
            float4v* op = (float4v*)(out + (size_t)v * 128 + 8 * q);
            __builtin_nontemporal_store((float4v){r[0], r[1], r[2], r[3]}, op);
            __builtin_nontemporal_store((float4v){r[4], r[5], r[6], r[7]}, op + 1);
        }
    }
}

// ---------------- agg2: persistent, one node per wave, 7 slots x 9 lanes, 3-in-flight ----------------
__global__ __launch_bounds__(256, 8) void k_agg_w72(
        const uint4* __restrict__ msg, const float* __restrict__ dinv,
        const int* __restrict__ rs, const int* __restrict__ deg,
        const int* __restrict__ csr, const float* __restrict__ bias,
        float* __restrict__ out, int n) {
    int lane = threadIdx.x & 63;
    int slot = lane / 9;
    int q = lane - slot * 9;
    bool active = lane < 63;
    int wid = blockIdx.x * 4 + (threadIdx.x >> 6);
    int nw = gridDim.x * 4;
    for (int v = wid; v < n; v += nw) {
        int start = rs[v];
        int cnt = deg[v];
        float dv = dinv[v];
        float acc[8] = {0.f, 0.f, 0.f, 0.f, 0.f, 0.f, 0.f, 0.f};
        uint4 mself = make_uint4(0, 0, 0, 0);
        if (active) {
            mself = msg[(size_t)v * 9 + q];
            int i = slot;
            for (; i + 14 < cnt; i += 21) {  // 3 gathers in flight per slot
                int s0 = csr[start + i];
                int s1 = csr[start + i + 7];
                int s2 = csr[start + i + 14];
                uint4 m0 = msg[(size_t)s0 * 9 + q];
                uint4 m1 = msg[(size_t)s1 * 9 + q];
                uint4 m2 = msg[(size_t)s2 * 9 + q];
                acc8(acc, m0);
                acc8(acc, m1);
                acc8(acc, m2);
            }
            for (; i + 7 < cnt; i += 14) {
                int s0 = csr[start + i];
                int s1 = csr[start + i + 7];
                uint4 m0 = msg[(size_t)s0 * 9 + q];
                uint4 m1 = msg[(size_t)s1 * 9 + q];
                acc8(acc, m0);
                acc8(acc, m1);
            }
            if (i < cnt) {
                int s = csr[start + i];
                uint4 m = msg[(size_t)s * 9 + q];
                acc8(acc, m);
            }
        }
#pragma unroll
        for (int j = 0; j < 8; j++) {
            float t27 = __shfl(acc[j], lane + 27);
            if (lane < 27) acc[j] += t27;
        }
#pragma unroll
        for (int j = 0; j < 8; j++) {
            float t54 = __shfl(acc[j], lane + 54);
            float t9  = __shfl(acc[j], lane + 9);
            float t18 = __shfl(acc[j], lane + 18);
            if (lane < 9) acc[j] += t54 + t9 + t18;
        }
        if (lane < 9) {
            float o[8];
            o[0] = acc[0] + bf_lo(mself.x); o[1] = acc[1] + bf_hi(mself.x);
            o[2] = acc[2] + bf_lo(mself.y); o[3] = acc[3] + bf_hi(mself.y);
            o[4] = acc[4] + bf_lo(mself.z); o[5] = acc[5] + bf_hi(mself.z);
            o[6] = acc[6] + bf_lo(mself.w); o[7] = acc[7] + bf_hi(mself.w);
            float* orow = out + (size_t)v * 70 + 8 * q;
#pragma unroll
            for (int jj = 0; jj < 4; jj++) {
                int f = 8 * q + 2 * jj;
                if (f < 70) {
                    float2 st = make_float2(dv * o[2 * jj] + bias[f],
                                            dv * o[2 * jj + 1] + bias[f + 1]);
                    *(float2*)(orow + 2 * jj) = st;  // cached: L2 coalesces partial lines
                }
            }
        }
    }
}

static inline size_t alignup(size_t x) { return (x + 255) & ~(size_t)255; }

extern "C" void kernel_launch(void* const* d_in, const int* in_sizes, int n_in,
                              void* d_out, int out_size, void* d_ws, size_t ws_size,
                              hipStream_t stream) {
    const float* x = (const float*)d_in[0];
    const int* edge = (const int*)d_in[1];
    const float* W1 = (const float*)d_in[2];
    const float* b1 = (const float*)d_in[3];
    const float* W2 = (const float*)d_in[4];
    const float* b2 = (const float*)d_in[5];

    const int N = in_sizes[0] / 128;
    const int E = in_sizes[1] / 2;
    const int* src = edge;
    const int* dst = edge + E;
    const int nb = (N + 255) >> BSH;

    char* w = (char*)d_ws;
    int* deg = (int*)w;              w += alignup((size_t)N * 4);
    float* dinv = (float*)w;         w += alignup((size_t)N * 4);
    int* rs = (int*)w;               w += alignup((size_t)N * 4);
    int* bwcur = (int*)w;            w += alignup(4096);
    int* csr = (int*)w;              w += alignup((size_t)nb * BCAP * 4);
    unsigned short* msg1 = (unsigned short*)w; w += alignup((size_t)N * 128 * 2);
    unsigned short* msg2 = (unsigned short*)w; w += alignup((size_t)N * 72 * 2);
    unsigned short* w1th = (unsigned short*)w; w += alignup(128 * 128 * 2);
    unsigned short* w1tl = (unsigned short*)w; w += alignup(128 * 128 * 2);
    unsigned short* w2th = (unsigned short*)w; w += alignup(80 * 128 * 2);
    unsigned short* w2tl = (unsigned short*)w; w += alignup(80 * 128 * 2);
    float* h = (float*)w;            w += alignup((size_t)N * 128 * 4);
    unsigned long long* tmp = (unsigned long long*)h;  // aliases h (disjoint in time)

    // ---- W pre-split + bwcur clear (one launch; precedes scatter on-stream) ----
    k_prep_w<<<104 + 2, 256, 0, stream>>>(W1, W2, w1th, w1tl, w2th, w2tl, bwcur);

    // ---- CSR build: direct bucketed scatter with CAP slack, 512-thread blocks ----
    k_bucket_scatter<<<(E + BCHUNK - 1) / BCHUNK, 512, 0, stream>>>(src, dst, bwcur, tmp, E, nb);
    k_bucket_finalize<<<nb, 512, 0, stream>>>(tmp, bwcur, deg, dinv, rs, csr, N);

    int gblocks = (N + 63) / 64;

    // Layer 1: msg1 = bf16(dinv * (x @ W1)) [N,128] ; agg -> h [N,128] fp32 (bias+relu)
    k_gemm_mfma<128, 128, 8><<<gblocks, 256, 0, stream>>>(x, w1th, w1tl, dinv, msg1, N);
    k_agg_w128<<<2048, 256, 0, stream>>>((const uint4*)msg1, dinv, rs, deg, csr, b1, h, N);

    // Layer 2: msg2 = bf16(dinv * (h @ W2)) [N,72 pad] ; agg -> d_out [N,70] (bias)
    k_gemm_mfma<70, 72, 5><<<gblocks, 256, 0, stream>>>(h, w2th, w2tl, dinv, msg2, N);
    k_agg_w72<<<2048, 256, 0, stream>>>((const uint4*)msg2, dinv, rs, deg, csr, b2,
                                        (float*)d_out, N);
}